// Round 13
// baseline (406.905 us; speedup 1.0000x reference)
//
#include <hip/hip_runtime.h>
#include <stdint.h>

// Problem constants
#define S_LEN 2048
#define EMB   1024
#define NH    16
#define DK    64
#define BATCH 2
#define MTOT  (BATCH * S_LEN)  // 4096

typedef __attribute__((ext_vector_type(8))) short    short8;
typedef __attribute__((ext_vector_type(4))) float    f32x4;
typedef __attribute__((ext_vector_type(4))) float    float4v;
typedef __attribute__((ext_vector_type(4))) unsigned uint4v;
typedef __attribute__((ext_vector_type(2))) unsigned uint2v;

__device__ __forceinline__ float b2f(short s) {
  unsigned u = ((unsigned)(unsigned short)s) << 16;
  return __builtin_bit_cast(float, u);
}
__device__ __forceinline__ short f2b(float f) {
  unsigned u = __builtin_bit_cast(unsigned, f);
  u = (u + 0x7FFFu + ((u >> 16) & 1u)) >> 16;  // RNE to bf16
  return (short)u;
}
// pack two f32 -> two bf16 in one uint (low = a, high = b)
__device__ __forceinline__ unsigned cvt2(float a, float b) {
  unsigned r;
  asm("v_cvt_pk_bf16_f32 %0, %1, %2" : "=v"(r) : "v"(a), "v"(b));
  return r;
}

// ---------------------------------------------------------------------------
// Fused f32 -> bf16 weight convert: grid (WSZ/4/256, 4), y picks the matrix.
// ---------------------------------------------------------------------------
__global__ __launch_bounds__(256) void cvt_w4(const float* __restrict__ w0,
                                              const float* __restrict__ w1,
                                              const float* __restrict__ w2,
                                              const float* __restrict__ w3,
                                              short* __restrict__ dst)
{
  const size_t WSZ = (size_t)EMB * EMB;
  const int y = blockIdx.y;
  const float* src = (y == 0) ? w0 : (y == 1) ? w1 : (y == 2) ? w2 : w3;
  short* d = dst + (size_t)y * WSZ;
  const int i = blockIdx.x * 256 + threadIdx.x;  // exact cover, no tail
  const f32x4 v = *(const f32x4*)(src + (size_t)i * 4);
  uint2v p;
  p[0] = cvt2(v[0], v[1]);
  p[1] = cvt2(v[2], v[3]);
  *(uint2v*)(d + (size_t)i * 4) = p;
}

// ---------------------------------------------------------------------------
// Shared NT-GEMM body, software-pipelined staging (unchanged from round 8).
// MODE 0: A = f32 (cvt to bf16 at LDS-write); out = bf16 scattered (B,H,S,DK).
// MODE 1: A = bf16; out = f32 row-major (M,N).
// ---------------------------------------------------------------------------
template <int MODE>
__device__ __forceinline__ void gemm_body(const float* __restrict__ Af0,
                                          const short* __restrict__ Ab0,
                                          const short* __restrict__ W,
                                          const float* __restrict__ bias,
                                          short* __restrict__ outb,
                                          float* __restrict__ outf,
                                          float scale, int m0, int n0)
{
  __shared__ __align__(16) unsigned Au[8][128][4];  // 16 KB
  __shared__ __align__(16) unsigned Bu[8][128][4];  // 16 KB
  const int tid = threadIdx.x;
  const int w = tid >> 6, l = tid & 63;
  const int g = l >> 4, r16 = l & 15;
  const int wr = w >> 1, wc = w & 1;
  const int srow = tid >> 3, shc = tid & 7;

  float4v acc[4][4];
#pragma unroll
  for (int i = 0; i < 4; ++i)
#pragma unroll
    for (int j = 0; j < 4; ++j)
      acc[i][j] = (float4v){0.f, 0.f, 0.f, 0.f};

  const float* Af = Af0 + (size_t)m0 * EMB;
  const short* Ab = Ab0 + (size_t)m0 * EMB;
  const short* Wbase = W + (size_t)n0 * EMB;

  f32x4  ax[4][2];
  uint4v apk[4];
  uint4v bpk[4];

#pragma unroll
  for (int p = 0; p < 4; ++p) {
    if constexpr (MODE == 0) {
      const float* src = Af + (size_t)(p * 32 + srow) * EMB + shc * 8;
      ax[p][0] = *(const f32x4*)src;
      ax[p][1] = *(const f32x4*)(src + 4);
    } else {
      apk[p] = __builtin_bit_cast(uint4v,
          *(const short8*)(Ab + (size_t)(p * 32 + srow) * EMB + shc * 8));
    }
    bpk[p] = __builtin_bit_cast(uint4v,
        *(const short8*)(Wbase + (size_t)(p * 32 + srow) * EMB + shc * 8));
  }

  for (int k0 = 0; k0 < EMB; k0 += 64) {
    uint4v awr[4], bwr[4];
#pragma unroll
    for (int p = 0; p < 4; ++p) {
      if constexpr (MODE == 0) {
        awr[p][0] = cvt2(ax[p][0][0], ax[p][0][1]);
        awr[p][1] = cvt2(ax[p][0][2], ax[p][0][3]);
        awr[p][2] = cvt2(ax[p][1][0], ax[p][1][1]);
        awr[p][3] = cvt2(ax[p][1][2], ax[p][1][3]);
      } else {
        awr[p] = apk[p];
      }
      bwr[p] = bpk[p];
    }

    __syncthreads();
#pragma unroll
    for (int p = 0; p < 4; ++p)
      *(uint4v*)&Au[shc][p * 32 + srow][0] = awr[p];
#pragma unroll
    for (int p = 0; p < 4; ++p)
      *(uint4v*)&Bu[shc][p * 32 + srow][0] = bwr[p];
    __syncthreads();

    if (k0 + 64 < EMB) {
      const int kn = k0 + 64;
#pragma unroll
      for (int p = 0; p < 4; ++p) {
        if constexpr (MODE == 0) {
          const float* src = Af + (size_t)(p * 32 + srow) * EMB + kn + shc * 8;
          ax[p][0] = *(const f32x4*)src;
          ax[p][1] = *(const f32x4*)(src + 4);
        } else {
          apk[p] = __builtin_bit_cast(uint4v,
              *(const short8*)(Ab + (size_t)(p * 32 + srow) * EMB + kn + shc * 8));
        }
        bpk[p] = __builtin_bit_cast(uint4v,
            *(const short8*)(Wbase + (size_t)(p * 32 + srow) * EMB + kn + shc * 8));
      }
    }

    __builtin_amdgcn_s_setprio(1);
#pragma unroll
    for (int ks = 0; ks < 2; ++ks) {
      const int c = ks * 4 + g;
      short8 af[4], bf[4];
#pragma unroll
      for (int i = 0; i < 4; ++i)
        af[i] = __builtin_bit_cast(short8, *(const uint4v*)&Au[c][wr * 64 + i * 16 + r16][0]);
#pragma unroll
      for (int j = 0; j < 4; ++j)
        bf[j] = __builtin_bit_cast(short8, *(const uint4v*)&Bu[c][wc * 64 + j * 16 + r16][0]);
#pragma unroll
      for (int i = 0; i < 4; ++i)
#pragma unroll
        for (int j = 0; j < 4; ++j)
          acc[i][j] = __builtin_amdgcn_mfma_f32_16x16x32_bf16(af[i], bf[j], acc[i][j], 0, 0, 0);
    }
    __builtin_amdgcn_s_setprio(0);
  }

#pragma unroll
  for (int j = 0; j < 4; ++j) {
    const int n = n0 + wc * 64 + j * 16 + r16;
    const float bv = bias[n];
#pragma unroll
    for (int i = 0; i < 4; ++i) {
#pragma unroll
      for (int r = 0; r < 4; ++r) {
        const int m = m0 + wr * 64 + i * 16 + g * 4 + r;
        const float vv = (acc[i][j][r] + bv) * scale;
        if constexpr (MODE == 0) {
          const int b = m >> 11, s = m & (S_LEN - 1);
          const int h = n >> 6, d = n & (DK - 1);
          outb[(size_t)((b * NH + h) * S_LEN + s) * DK + d] = f2b(vv);
        } else {
          outf[(size_t)m * EMB + n] = vv;
        }
      }
    }
  }
}

// Fused Q/K/V projections: grid 768 blocks.
// Q output pre-scaled by (1/sqrt(dk)) * log2(e) for exp2-domain softmax.
__global__ __launch_bounds__(256, 2) void gemm_qkv(const float* __restrict__ q,
                                                   const float* __restrict__ k,
                                                   const float* __restrict__ v,
                                                   const short* __restrict__ Wb,
                                                   const float* __restrict__ bq,
                                                   const float* __restrict__ bk,
                                                   const float* __restrict__ bv,
                                                   short* __restrict__ Qp,
                                                   short* __restrict__ Kp,
                                                   short* __restrict__ Vp)
{
  const int which = blockIdx.x >> 8;
  const int inner = blockIdx.x & 255;
  const int lin = (inner & 7) * 32 + (inner >> 3);  // XCD swizzle
  const int m0 = (lin >> 3) * 128, n0 = (lin & 7) * 128;
  const float* A    = (which == 0) ? q  : (which == 1) ? k  : v;
  const float* bias = (which == 0) ? bq : (which == 1) ? bk : bv;
  short* out        = (which == 0) ? Qp : (which == 1) ? Kp : Vp;
  const short* W = Wb + (size_t)which * EMB * EMB;
  const float scale = (which == 0) ? 0.125f * 1.44269504088896f : 1.0f;
  gemm_body<0>(A, nullptr, W, bias, out, nullptr, scale, m0, n0);
}

__global__ __launch_bounds__(256, 2) void gemm_out(const short* __restrict__ Cx,
                                                   const short* __restrict__ Wob,
                                                   const float* __restrict__ bo,
                                                   float* __restrict__ outp)
{
  const int lin = (blockIdx.x & 7) * 32 + (blockIdx.x >> 3);
  gemm_body<1>(nullptr, Cx, Wob, bo, nullptr, outp, 1.0f, (lin >> 3) * 128, (lin & 7) * 128);
}

// ---------------------------------------------------------------------------
// Flash attention with KV-SPLIT 2 (r12) + NON-TEMPORAL partial-O/lse stores
// (r13 fix): the split's write-allocate footprint (~2 MB/XCD of op0/op1
// dirty lines) pushed the per-XCD L2 working set past 4 MB and thrashed the
// K/V stream (FETCH 12->578 MB). Partial O and lse are write-once/read-once
// by a later kernel -> nt stores keep them out of L2 entirely.
// ---------------------------------------------------------------------------
__global__ __launch_bounds__(256, 4) void attn_kernel(const short* __restrict__ Qp,
                                                      const short* __restrict__ Kp,
                                                      const short* __restrict__ Vp,
                                                      short* __restrict__ op0,
                                                      short* __restrict__ op1,
                                                      float* __restrict__ lseB)
{
  __shared__ __align__(16) unsigned Vtu[2][64][36];     // 18432 B
  __shared__ __align__(16) unsigned Plu[4][2][16][36];  // 18432 B
  const int tid = threadIdx.x;
  const int w = tid >> 6, l = tid & 63;
  const int g = l >> 4, r16 = l & 15;
  const int lin = (blockIdx.x & 7) * 128 + (blockIdx.x >> 3);  // XCD swizzle
  const int bh = lin >> 5;                          // b*NH + h (4 per XCD)
  const int rest = lin & 31;
  const int split = rest >> 4;                      // kv half
  const int q0 = (rest & 15) * 128 + w * 32;        // wave's 32 q rows
  const int kvbase = split * (S_LEN / 2);
  short* op = split ? op1 : op0;
  const short* Qb = Qp + (size_t)bh * S_LEN * DK;
  const short* Kb = Kp + (size_t)bh * S_LEN * DK;
  const short* Vb = Vp + (size_t)bh * S_LEN * DK;

  const short8 qf0a = *(const short8*)(Qb + (size_t)(q0 + r16) * DK + g * 8);
  const short8 qf1a = *(const short8*)(Qb + (size_t)(q0 + r16) * DK + 32 + g * 8);
  const short8 qf0b = *(const short8*)(Qb + (size_t)(q0 + 16 + r16) * DK + g * 8);
  const short8 qf1b = *(const short8*)(Qb + (size_t)(q0 + 16 + r16) * DK + 32 + g * 8);

  const short one_b = (short)0x3F80;
  const short8 ones8 = {one_b, one_b, one_b, one_b, one_b, one_b, one_b, one_b};

  float4v oa[4], ob[4];
#pragma unroll
  for (int j = 0; j < 4; ++j) {
    oa[j] = (float4v){0.f, 0.f, 0.f, 0.f};
    ob[j] = (float4v){0.f, 0.f, 0.f, 0.f};
  }
  float4v lacc_a = (float4v){0.f, 0.f, 0.f, 0.f};
  float4v lacc_b = (float4v){0.f, 0.f, 0.f, 0.f};
  float m_a = -3.0e38f, m_b = -3.0e38f;   // running max for q = l&15

  const int va  = tid >> 3;
  const int vdb = (tid & 7) * 8;
  const int vcs = va ^ ((tid & 7) << 2);

  // --- prefetch tile 0 of this split ---
  short8 vr0 = *(const short8*)(Vb + (size_t)(kvbase + 2 * va) * DK + vdb);
  short8 vr1 = *(const short8*)(Vb + (size_t)(kvbase + 2 * va + 1) * DK + vdb);
  short8 kr0[4], kr1[4];
#pragma unroll
  for (int s = 0; s < 4; ++s) {
    kr0[s] = *(const short8*)(Kb + (size_t)(kvbase + s * 16 + r16) * DK + g * 8);
    kr1[s] = *(const short8*)(Kb + (size_t)(kvbase + s * 16 + r16) * DK + 32 + g * 8);
  }

  for (int t = 0; t < S_LEN / 2 / 64; ++t) {
    const int buf = t & 1;
#pragma unroll
    for (int i = 0; i < 8; ++i) {
      const unsigned pk = ((unsigned)(unsigned short)vr0[i]) |
                          (((unsigned)(unsigned short)vr1[i]) << 16);
      Vtu[buf][vdb + i][vcs] = pk;
    }

    // --- QK^T both subtiles, shared K fragments ---
    float4v sa[4], sb[4];
    __builtin_amdgcn_s_setprio(1);
#pragma unroll
    for (int s = 0; s < 4; ++s) {
      float4v x = (float4v){0.f, 0.f, 0.f, 0.f};
      x = __builtin_amdgcn_mfma_f32_16x16x32_bf16(kr0[s], qf0a, x, 0, 0, 0);
      x = __builtin_amdgcn_mfma_f32_16x16x32_bf16(kr1[s], qf1a, x, 0, 0, 0);
      sa[s] = x;
      float4v y = (float4v){0.f, 0.f, 0.f, 0.f};
      y = __builtin_amdgcn_mfma_f32_16x16x32_bf16(kr0[s], qf0b, y, 0, 0, 0);
      y = __builtin_amdgcn_mfma_f32_16x16x32_bf16(kr1[s], qf1b, y, 0, 0, 0);
      sb[s] = y;
    }
    __builtin_amdgcn_s_setprio(0);

    // --- prefetch V,K for next tile (wraps within split; harmless) ---
    const int nkv = kvbase + (((t + 1) & (S_LEN / 2 / 64 - 1)) * 64);
    vr0 = *(const short8*)(Vb + (size_t)(nkv + 2 * va) * DK + vdb);
    vr1 = *(const short8*)(Vb + (size_t)(nkv + 2 * va + 1) * DK + vdb);
#pragma unroll
    for (int s = 0; s < 4; ++s) {
      kr0[s] = *(const short8*)(Kb + (size_t)(nkv + s * 16 + r16) * DK + g * 8);
      kr1[s] = *(const short8*)(Kb + (size_t)(nkv + s * 16 + r16) * DK + 32 + g * 8);
    }

    // --- per-lane tile max ---
    float mxa[4], mxb[4];
#pragma unroll
    for (int s = 0; s < 4; ++s) {
      mxa[s] = fmaxf(fmaxf(sa[s][0], sa[s][1]), fmaxf(sa[s][2], sa[s][3]));
      mxb[s] = fmaxf(fmaxf(sb[s][0], sb[s][1]), fmaxf(sb[s][2], sb[s][3]));
    }
    const float mta_l = fmaxf(fmaxf(mxa[0], mxa[1]), fmaxf(mxa[2], mxa[3]));
    const float mtb_l = fmaxf(fmaxf(mxb[0], mxb[1]), fmaxf(mxb[2], mxb[3]));

    const int okk = (mta_l <= m_a + 8.f) && (mtb_l <= m_b + 8.f);
    if (__all(okk)) {
      // fast path: keep old max (P bounded by 2^8); no rescale
#pragma unroll
      for (int s = 0; s < 4; ++s) {
        const float a0 = exp2f(sa[s][0] - m_a), a1 = exp2f(sa[s][1] - m_a);
        const float a2 = exp2f(sa[s][2] - m_a), a3 = exp2f(sa[s][3] - m_a);
        Plu[w][0][r16][s * 8 + g * 2]     = cvt2(a0, a1);
        Plu[w][0][r16][s * 8 + g * 2 + 1] = cvt2(a2, a3);
        const float b0 = exp2f(sb[s][0] - m_b), b1 = exp2f(sb[s][1] - m_b);
        const float b2 = exp2f(sb[s][2] - m_b), b3 = exp2f(sb[s][3] - m_b);
        Plu[w][1][r16][s * 8 + g * 2]     = cvt2(b0, b1);
        Plu[w][1][r16][s * 8 + g * 2 + 1] = cvt2(b2, b3);
      }
    } else {
      // full path: cross-lane max, rescale O and l accumulators
      float mta = fmaxf(mta_l, __shfl_xor(mta_l, 16));
      float mtb = fmaxf(mtb_l, __shfl_xor(mtb_l, 16));
      mta = fmaxf(mta, __shfl_xor(mta, 32));
      mtb = fmaxf(mtb, __shfl_xor(mtb, 32));
      const float mna = fmaxf(m_a, mta);
      const float mnb = fmaxf(m_b, mtb);
      const float ala = exp2f(m_a - mna);
      const float alb = exp2f(m_b - mnb);
      const float aa0 = __shfl(ala, g * 4 + 0), ab0 = __shfl(alb, g * 4 + 0);
      const float aa1 = __shfl(ala, g * 4 + 1), ab1 = __shfl(alb, g * 4 + 1);
      const float aa2 = __shfl(ala, g * 4 + 2), ab2 = __shfl(alb, g * 4 + 2);
      const float aa3 = __shfl(ala, g * 4 + 3), ab3 = __shfl(alb, g * 4 + 3);
#pragma unroll
      for (int j = 0; j < 4; ++j) {
        oa[j][0] *= aa0; oa[j][1] *= aa1; oa[j][2] *= aa2; oa[j][3] *= aa3;
        ob[j][0] *= ab0; ob[j][1] *= ab1; ob[j][2] *= ab2; ob[j][3] *= ab3;
      }
      lacc_a[0] *= aa0; lacc_a[1] *= aa1; lacc_a[2] *= aa2; lacc_a[3] *= aa3;
      lacc_b[0] *= ab0; lacc_b[1] *= ab1; lacc_b[2] *= ab2; lacc_b[3] *= ab3;
#pragma unroll
      for (int s = 0; s < 4; ++s) {
        const float a0 = exp2f(sa[s][0] - mna), a1 = exp2f(sa[s][1] - mna);
        const float a2 = exp2f(sa[s][2] - mna), a3 = exp2f(sa[s][3] - mna);
        Plu[w][0][r16][s * 8 + g * 2]     = cvt2(a0, a1);
        Plu[w][0][r16][s * 8 + g * 2 + 1] = cvt2(a2, a3);
        const float b0 = exp2f(sb[s][0] - mnb), b1 = exp2f(sb[s][1] - mnb);
        const float b2 = exp2f(sb[s][2] - mnb), b3 = exp2f(sb[s][3] - mnb);
        Plu[w][1][r16][s * 8 + g * 2]     = cvt2(b0, b1);
        Plu[w][1][r16][s * 8 + g * 2 + 1] = cvt2(b2, b3);
      }
      m_a = mna; m_b = mnb;
    }

    __syncthreads();

    // --- PV + l-sum ---
    __builtin_amdgcn_s_setprio(1);
#pragma unroll
    for (int kc = 0; kc < 2; ++kc) {
      const short8 pfa = __builtin_bit_cast(short8, *(const uint4v*)&Plu[w][0][r16][kc * 16 + g * 4]);
      const short8 pfb = __builtin_bit_cast(short8, *(const uint4v*)&Plu[w][1][r16][kc * 16 + g * 4]);
      lacc_a = __builtin_amdgcn_mfma_f32_16x16x32_bf16(pfa, ones8, lacc_a, 0, 0, 0);
      lacc_b = __builtin_amdgcn_mfma_f32_16x16x32_bf16(pfb, ones8, lacc_b, 0, 0, 0);
#pragma unroll
      for (int j = 0; j < 4; ++j) {
        const int h = (2 * j + (r16 >> 3)) & 7;
        const short8 vf = __builtin_bit_cast(short8,
            *(const uint4v*)&Vtu[buf][j * 16 + r16][4 * (((kc << 2) + g) ^ h)]);
        oa[j] = __builtin_amdgcn_mfma_f32_16x16x32_bf16(pfa, vf, oa[j], 0, 0, 0);
        ob[j] = __builtin_amdgcn_mfma_f32_16x16x32_bf16(pfb, vf, ob[j], 0, 0, 0);
      }
    }
    __builtin_amdgcn_s_setprio(0);
  }

  // --- finalize split: normalized O + lse, all stores NON-TEMPORAL ---
  const float ria0 = 1.f / lacc_a[0], rib0 = 1.f / lacc_b[0];
  const float ria1 = 1.f / lacc_a[1], rib1 = 1.f / lacc_b[1];
  const float ria2 = 1.f / lacc_a[2], rib2 = 1.f / lacc_b[2];
  const float ria3 = 1.f / lacc_a[3], rib3 = 1.f / lacc_b[3];
  const int b = bh >> 4, h = bh & 15;
#pragma unroll
  for (int j = 0; j < 4; ++j) {
    const int d = h * DK + j * 16 + r16;
    const int qa = q0 + g * 4;
    const int qb2 = q0 + 16 + g * 4;
    __builtin_nontemporal_store(f2b(oa[j][0] * ria0), &op[(size_t)(b * S_LEN + qa + 0) * EMB + d]);
    __builtin_nontemporal_store(f2b(oa[j][1] * ria1), &op[(size_t)(b * S_LEN + qa + 1) * EMB + d]);
    __builtin_nontemporal_store(f2b(oa[j][2] * ria2), &op[(size_t)(b * S_LEN + qa + 2) * EMB + d]);
    __builtin_nontemporal_store(f2b(oa[j][3] * ria3), &op[(size_t)(b * S_LEN + qa + 3) * EMB + d]);
    __builtin_nontemporal_store(f2b(ob[j][0] * rib0), &op[(size_t)(b * S_LEN + qb2 + 0) * EMB + d]);
    __builtin_nontemporal_store(f2b(ob[j][1] * rib1), &op[(size_t)(b * S_LEN + qb2 + 1) * EMB + d]);
    __builtin_nontemporal_store(f2b(ob[j][2] * rib2), &op[(size_t)(b * S_LEN + qb2 + 2) * EMB + d]);
    __builtin_nontemporal_store(f2b(ob[j][3] * rib3), &op[(size_t)(b * S_LEN + qb2 + 3) * EMB + d]);
  }

  // m broadcasts with ALL lanes active (r12 fix), predicated nt store.
  const float sma0 = __shfl(m_a, g * 4 + 0), smb0 = __shfl(m_b, g * 4 + 0);
  const float sma1 = __shfl(m_a, g * 4 + 1), smb1 = __shfl(m_b, g * 4 + 1);
  const float sma2 = __shfl(m_a, g * 4 + 2), smb2 = __shfl(m_b, g * 4 + 2);
  const float sma3 = __shfl(m_a, g * 4 + 3), smb3 = __shfl(m_b, g * 4 + 3);
  if (r16 == 0) {
    float* lp = lseB + (size_t)split * (BATCH * NH * S_LEN) + (size_t)bh * S_LEN;
    __builtin_nontemporal_store(sma0 + __log2f(lacc_a[0]), &lp[q0 + g * 4 + 0]);
    __builtin_nontemporal_store(sma1 + __log2f(lacc_a[1]), &lp[q0 + g * 4 + 1]);
    __builtin_nontemporal_store(sma2 + __log2f(lacc_a[2]), &lp[q0 + g * 4 + 2]);
    __builtin_nontemporal_store(sma3 + __log2f(lacc_a[3]), &lp[q0 + g * 4 + 3]);
    __builtin_nontemporal_store(smb0 + __log2f(lacc_b[0]), &lp[q0 + 16 + g * 4 + 0]);
    __builtin_nontemporal_store(smb1 + __log2f(lacc_b[1]), &lp[q0 + 16 + g * 4 + 1]);
    __builtin_nontemporal_store(smb2 + __log2f(lacc_b[2]), &lp[q0 + 16 + g * 4 + 2]);
    __builtin_nontemporal_store(smb3 + __log2f(lacc_b[3]), &lp[q0 + 16 + g * 4 + 3]);
  }
}

// ---------------------------------------------------------------------------
// Combine the two kv-splits: O = (O0*2^(lse0-m) + O1*2^(lse1-m)) / (sum w).
// nt loads (read-once streams); normal store of Cx (reused by gemm_out).
// ---------------------------------------------------------------------------
__global__ __launch_bounds__(256) void combine2(const short* __restrict__ op1,
                                                const float* __restrict__ lseB,
                                                short* __restrict__ cx /* = op0 */)
{
  const int c = blockIdx.x * 256 + threadIdx.x;   // 8-elem chunk, exact cover
  const size_t e = (size_t)c * 8;
  const int row = (int)(e >> 10);          // b*S + s
  const int col = (int)(e & 1023);
  const int h = col >> 6;
  const int b = row >> 11, s = row & (S_LEN - 1);
  const int li = (b * NH + h) * S_LEN + s;
  const float l0 = lseB[li];
  const float l1 = lseB[BATCH * NH * S_LEN + li];
  const float wm = fmaxf(l0, l1);
  const float w0 = exp2f(l0 - wm), w1 = exp2f(l1 - wm);
  const float inv = 1.f / (w0 + w1);
  const float f0 = w0 * inv, f1 = w1 * inv;
  const short8 a = __builtin_nontemporal_load((const short8*)(cx + e));
  const short8 d = __builtin_nontemporal_load((const short8*)(op1 + e));
  short8 o;
#pragma unroll
  for (int i = 0; i < 8; ++i)
    o[i] = f2b(b2f(a[i]) * f0 + b2f(d[i]) * f1);
  *(short8*)(cx + e) = o;
}

// ---------------------------------------------------------------------------
extern "C" void kernel_launch(void* const* d_in, const int* in_sizes, int n_in,
                              void* d_out, int out_size, void* d_ws, size_t ws_size,
                              hipStream_t stream)
{
  const float* q  = (const float*)d_in[0];
  const float* k  = (const float*)d_in[1];
  const float* v  = (const float*)d_in[2];
  const float* Wq = (const float*)d_in[3];
  const float* bq = (const float*)d_in[4];
  const float* Wk = (const float*)d_in[5];
  const float* bk = (const float*)d_in[6];
  const float* Wv = (const float*)d_in[7];
  const float* bv = (const float*)d_in[8];
  const float* Wo = (const float*)d_in[9];
  const float* bo = (const float*)d_in[10];

  short* ws = (short*)d_ws;
  const size_t WSZ  = (size_t)EMB * EMB;   // 1M elems per weight matrix
  const size_t PROJ = (size_t)MTOT * EMB;  // 4M elems per activation
  short* Wb   = ws;                // bf16 weights: Wq,Wk,Wv consecutive + Wo
  short* Wob  = ws + 3 * WSZ;
  short* Qp   = ws + 4 * WSZ;      // (B,H,S,DK) bf16, pre-scaled
  short* Vp   = Qp + PROJ;
  short* Cx   = Vp + PROJ;         // split-0 partial O, then combined context
  // lse buffer (512 KB) aliases the Wq-bf16 region: Wq copy is consumed by
  // gemm_qkv before attn writes lse; cvt_w4 rewrites it every call.
  float* lseB = (float*)ws;
  short* Kp   = (short*)d_out;                // K parks in d_out lower half
  short* Op1  = (short*)d_out + PROJ;         // split-1 partial O, upper half

  cvt_w4<<<dim3((int)(WSZ / 4 / 256), 4), dim3(256), 0, stream>>>(Wq, Wk, Wv, Wo, ws);

  gemm_qkv<<<dim3(768), dim3(256), 0, stream>>>(q, k, v, Wb, bq, bk, bv, Qp, Kp, Vp);
  attn_kernel<<<dim3(1024), dim3(256), 0, stream>>>(Qp, Kp, Vp, Cx, Op1, lseB);
  combine2<<<dim3((int)(PROJ / 8 / 256)), dim3(256), 0, stream>>>(Op1, lseB, Cx);
  gemm_out<<<dim3(256), dim3(256), 0, stream>>>(Cx, Wob, bo, (float*)d_out);
}

// Round 14
// 178.275 us; speedup vs baseline: 2.2825x; 2.2825x over previous
//
#include <hip/hip_runtime.h>
#include <stdint.h>

// Problem constants
#define S_LEN 2048
#define EMB   1024
#define NH    16
#define DK    64
#define BATCH 2
#define MTOT  (BATCH * S_LEN)  // 4096

typedef __attribute__((ext_vector_type(8))) short    short8;
typedef __attribute__((ext_vector_type(4))) float    f32x4;
typedef __attribute__((ext_vector_type(4))) float    float4v;
typedef __attribute__((ext_vector_type(4))) unsigned uint4v;
typedef __attribute__((ext_vector_type(2))) unsigned uint2v;

__device__ __forceinline__ float b2f(short s) {
  unsigned u = ((unsigned)(unsigned short)s) << 16;
  return __builtin_bit_cast(float, u);
}
__device__ __forceinline__ short f2b(float f) {
  unsigned u = __builtin_bit_cast(unsigned, f);
  u = (u + 0x7FFFu + ((u >> 16) & 1u)) >> 16;  // RNE to bf16
  return (short)u;
}
// pack two f32 -> two bf16 in one uint (low = a, high = b)
__device__ __forceinline__ unsigned cvt2(float a, float b) {
  unsigned r;
  asm("v_cvt_pk_bf16_f32 %0, %1, %2" : "=v"(r) : "v"(a), "v"(b));
  return r;
}

// ---------------------------------------------------------------------------
// Fused f32 -> bf16 weight convert: grid (WSZ/4/256, 4), y picks the matrix.
// ---------------------------------------------------------------------------
__global__ __launch_bounds__(256) void cvt_w4(const float* __restrict__ w0,
                                              const float* __restrict__ w1,
                                              const float* __restrict__ w2,
                                              const float* __restrict__ w3,
                                              short* __restrict__ dst)
{
  const size_t WSZ = (size_t)EMB * EMB;
  const int y = blockIdx.y;
  const float* src = (y == 0) ? w0 : (y == 1) ? w1 : (y == 2) ? w2 : w3;
  short* d = dst + (size_t)y * WSZ;
  const int i = blockIdx.x * 256 + threadIdx.x;  // exact cover, no tail
  const f32x4 v = *(const f32x4*)(src + (size_t)i * 4);
  uint2v p;
  p[0] = cvt2(v[0], v[1]);
  p[1] = cvt2(v[2], v[3]);
  *(uint2v*)(d + (size_t)i * 4) = p;
}

// ---------------------------------------------------------------------------
// Shared NT-GEMM body, software-pipelined staging (unchanged from round 8).
// MODE 0: A = f32 (cvt to bf16 at LDS-write); out = bf16 scattered (B,H,S,DK).
// MODE 1: A = bf16; out = f32 row-major (M,N).
// ---------------------------------------------------------------------------
template <int MODE>
__device__ __forceinline__ void gemm_body(const float* __restrict__ Af0,
                                          const short* __restrict__ Ab0,
                                          const short* __restrict__ W,
                                          const float* __restrict__ bias,
                                          short* __restrict__ outb,
                                          float* __restrict__ outf,
                                          float scale, int m0, int n0)
{
  __shared__ __align__(16) unsigned Au[8][128][4];  // 16 KB
  __shared__ __align__(16) unsigned Bu[8][128][4];  // 16 KB
  const int tid = threadIdx.x;
  const int w = tid >> 6, l = tid & 63;
  const int g = l >> 4, r16 = l & 15;
  const int wr = w >> 1, wc = w & 1;
  const int srow = tid >> 3, shc = tid & 7;

  float4v acc[4][4];
#pragma unroll
  for (int i = 0; i < 4; ++i)
#pragma unroll
    for (int j = 0; j < 4; ++j)
      acc[i][j] = (float4v){0.f, 0.f, 0.f, 0.f};

  const float* Af = Af0 + (size_t)m0 * EMB;
  const short* Ab = Ab0 + (size_t)m0 * EMB;
  const short* Wbase = W + (size_t)n0 * EMB;

  f32x4  ax[4][2];
  uint4v apk[4];
  uint4v bpk[4];

#pragma unroll
  for (int p = 0; p < 4; ++p) {
    if constexpr (MODE == 0) {
      const float* src = Af + (size_t)(p * 32 + srow) * EMB + shc * 8;
      ax[p][0] = *(const f32x4*)src;
      ax[p][1] = *(const f32x4*)(src + 4);
    } else {
      apk[p] = __builtin_bit_cast(uint4v,
          *(const short8*)(Ab + (size_t)(p * 32 + srow) * EMB + shc * 8));
    }
    bpk[p] = __builtin_bit_cast(uint4v,
        *(const short8*)(Wbase + (size_t)(p * 32 + srow) * EMB + shc * 8));
  }

  for (int k0 = 0; k0 < EMB; k0 += 64) {
    uint4v awr[4], bwr[4];
#pragma unroll
    for (int p = 0; p < 4; ++p) {
      if constexpr (MODE == 0) {
        awr[p][0] = cvt2(ax[p][0][0], ax[p][0][1]);
        awr[p][1] = cvt2(ax[p][0][2], ax[p][0][3]);
        awr[p][2] = cvt2(ax[p][1][0], ax[p][1][1]);
        awr[p][3] = cvt2(ax[p][1][2], ax[p][1][3]);
      } else {
        awr[p] = apk[p];
      }
      bwr[p] = bpk[p];
    }

    __syncthreads();
#pragma unroll
    for (int p = 0; p < 4; ++p)
      *(uint4v*)&Au[shc][p * 32 + srow][0] = awr[p];
#pragma unroll
    for (int p = 0; p < 4; ++p)
      *(uint4v*)&Bu[shc][p * 32 + srow][0] = bwr[p];
    __syncthreads();

    if (k0 + 64 < EMB) {
      const int kn = k0 + 64;
#pragma unroll
      for (int p = 0; p < 4; ++p) {
        if constexpr (MODE == 0) {
          const float* src = Af + (size_t)(p * 32 + srow) * EMB + kn + shc * 8;
          ax[p][0] = *(const f32x4*)src;
          ax[p][1] = *(const f32x4*)(src + 4);
        } else {
          apk[p] = __builtin_bit_cast(uint4v,
              *(const short8*)(Ab + (size_t)(p * 32 + srow) * EMB + kn + shc * 8));
        }
        bpk[p] = __builtin_bit_cast(uint4v,
            *(const short8*)(Wbase + (size_t)(p * 32 + srow) * EMB + kn + shc * 8));
      }
    }

    __builtin_amdgcn_s_setprio(1);
#pragma unroll
    for (int ks = 0; ks < 2; ++ks) {
      const int c = ks * 4 + g;
      short8 af[4], bf[4];
#pragma unroll
      for (int i = 0; i < 4; ++i)
        af[i] = __builtin_bit_cast(short8, *(const uint4v*)&Au[c][wr * 64 + i * 16 + r16][0]);
#pragma unroll
      for (int j = 0; j < 4; ++j)
        bf[j] = __builtin_bit_cast(short8, *(const uint4v*)&Bu[c][wc * 64 + j * 16 + r16][0]);
#pragma unroll
      for (int i = 0; i < 4; ++i)
#pragma unroll
        for (int j = 0; j < 4; ++j)
          acc[i][j] = __builtin_amdgcn_mfma_f32_16x16x32_bf16(af[i], bf[j], acc[i][j], 0, 0, 0);
    }
    __builtin_amdgcn_s_setprio(0);
  }

#pragma unroll
  for (int j = 0; j < 4; ++j) {
    const int n = n0 + wc * 64 + j * 16 + r16;
    const float bv = bias[n];
#pragma unroll
    for (int i = 0; i < 4; ++i) {
#pragma unroll
      for (int r = 0; r < 4; ++r) {
        const int m = m0 + wr * 64 + i * 16 + g * 4 + r;
        const float vv = (acc[i][j][r] + bv) * scale;
        if constexpr (MODE == 0) {
          const int b = m >> 11, s = m & (S_LEN - 1);
          const int h = n >> 6, d = n & (DK - 1);
          outb[(size_t)((b * NH + h) * S_LEN + s) * DK + d] = f2b(vv);
        } else {
          outf[(size_t)m * EMB + n] = vv;
        }
      }
    }
  }
}

// Fused Q/K/V projections: grid 768 blocks.
// Q output pre-scaled by (1/sqrt(dk)) * log2(e) for exp2-domain softmax.
__global__ __launch_bounds__(256, 2) void gemm_qkv(const float* __restrict__ q,
                                                   const float* __restrict__ k,
                                                   const float* __restrict__ v,
                                                   const short* __restrict__ Wb,
                                                   const float* __restrict__ bq,
                                                   const float* __restrict__ bk,
                                                   const float* __restrict__ bv,
                                                   short* __restrict__ Qp,
                                                   short* __restrict__ Kp,
                                                   short* __restrict__ Vp)
{
  const int which = blockIdx.x >> 8;
  const int inner = blockIdx.x & 255;
  const int lin = (inner & 7) * 32 + (inner >> 3);  // XCD swizzle
  const int m0 = (lin >> 3) * 128, n0 = (lin & 7) * 128;
  const float* A    = (which == 0) ? q  : (which == 1) ? k  : v;
  const float* bias = (which == 0) ? bq : (which == 1) ? bk : bv;
  short* out        = (which == 0) ? Qp : (which == 1) ? Kp : Vp;
  const short* W = Wb + (size_t)which * EMB * EMB;
  const float scale = (which == 0) ? 0.125f * 1.44269504088896f : 1.0f;
  gemm_body<0>(A, nullptr, W, bias, out, nullptr, scale, m0, n0);
}

__global__ __launch_bounds__(256, 2) void gemm_out(const short* __restrict__ Cx,
                                                   const short* __restrict__ Wob,
                                                   const float* __restrict__ bo,
                                                   float* __restrict__ outp)
{
  const int lin = (blockIdx.x & 7) * 32 + (blockIdx.x >> 3);
  gemm_body<1>(nullptr, Cx, Wob, bo, nullptr, outp, 1.0f, (lin >> 3) * 128, (lin & 7) * 128);
}

// ---------------------------------------------------------------------------
// Flash attention with KV-SPLIT 2. r14 fix: __launch_bounds__(256,2) —
// r11's (256,4) clamped VGPR 104->64 and caused a scratch-spill storm
// (577 MB reads + 855 MB writes of spill traffic; nt stores were a no-op
// because the traffic was scratch, not partial-O). Natural VGPR ~104 gives
// 16 waves/CU by the register table and LDS 36KB allows 4 blocks/CU, so the
// 1024-block grid still reaches the split's occupancy goal without a clamp.
// ---------------------------------------------------------------------------
__global__ __launch_bounds__(256, 2) void attn_kernel(const short* __restrict__ Qp,
                                                      const short* __restrict__ Kp,
                                                      const short* __restrict__ Vp,
                                                      short* __restrict__ op0,
                                                      short* __restrict__ op1,
                                                      float* __restrict__ lseB)
{
  __shared__ __align__(16) unsigned Vtu[2][64][36];     // 18432 B
  __shared__ __align__(16) unsigned Plu[4][2][16][36];  // 18432 B
  const int tid = threadIdx.x;
  const int w = tid >> 6, l = tid & 63;
  const int g = l >> 4, r16 = l & 15;
  const int lin = (blockIdx.x & 7) * 128 + (blockIdx.x >> 3);  // XCD swizzle
  const int bh = lin >> 5;                          // b*NH + h (4 per XCD)
  const int rest = lin & 31;
  const int split = rest >> 4;                      // kv half
  const int q0 = (rest & 15) * 128 + w * 32;        // wave's 32 q rows
  const int kvbase = split * (S_LEN / 2);
  short* op = split ? op1 : op0;
  const short* Qb = Qp + (size_t)bh * S_LEN * DK;
  const short* Kb = Kp + (size_t)bh * S_LEN * DK;
  const short* Vb = Vp + (size_t)bh * S_LEN * DK;

  const short8 qf0a = *(const short8*)(Qb + (size_t)(q0 + r16) * DK + g * 8);
  const short8 qf1a = *(const short8*)(Qb + (size_t)(q0 + r16) * DK + 32 + g * 8);
  const short8 qf0b = *(const short8*)(Qb + (size_t)(q0 + 16 + r16) * DK + g * 8);
  const short8 qf1b = *(const short8*)(Qb + (size_t)(q0 + 16 + r16) * DK + 32 + g * 8);

  const short one_b = (short)0x3F80;
  const short8 ones8 = {one_b, one_b, one_b, one_b, one_b, one_b, one_b, one_b};

  float4v oa[4], ob[4];
#pragma unroll
  for (int j = 0; j < 4; ++j) {
    oa[j] = (float4v){0.f, 0.f, 0.f, 0.f};
    ob[j] = (float4v){0.f, 0.f, 0.f, 0.f};
  }
  float4v lacc_a = (float4v){0.f, 0.f, 0.f, 0.f};
  float4v lacc_b = (float4v){0.f, 0.f, 0.f, 0.f};
  float m_a = -3.0e38f, m_b = -3.0e38f;   // running max for q = l&15

  const int va  = tid >> 3;
  const int vdb = (tid & 7) * 8;
  const int vcs = va ^ ((tid & 7) << 2);

  // --- prefetch tile 0 of this split ---
  short8 vr0 = *(const short8*)(Vb + (size_t)(kvbase + 2 * va) * DK + vdb);
  short8 vr1 = *(const short8*)(Vb + (size_t)(kvbase + 2 * va + 1) * DK + vdb);
  short8 kr0[4], kr1[4];
#pragma unroll
  for (int s = 0; s < 4; ++s) {
    kr0[s] = *(const short8*)(Kb + (size_t)(kvbase + s * 16 + r16) * DK + g * 8);
    kr1[s] = *(const short8*)(Kb + (size_t)(kvbase + s * 16 + r16) * DK + 32 + g * 8);
  }

  for (int t = 0; t < S_LEN / 2 / 64; ++t) {
    const int buf = t & 1;
#pragma unroll
    for (int i = 0; i < 8; ++i) {
      const unsigned pk = ((unsigned)(unsigned short)vr0[i]) |
                          (((unsigned)(unsigned short)vr1[i]) << 16);
      Vtu[buf][vdb + i][vcs] = pk;
    }

    // --- QK^T both subtiles, shared K fragments ---
    float4v sa[4], sb[4];
    __builtin_amdgcn_s_setprio(1);
#pragma unroll
    for (int s = 0; s < 4; ++s) {
      float4v x = (float4v){0.f, 0.f, 0.f, 0.f};
      x = __builtin_amdgcn_mfma_f32_16x16x32_bf16(kr0[s], qf0a, x, 0, 0, 0);
      x = __builtin_amdgcn_mfma_f32_16x16x32_bf16(kr1[s], qf1a, x, 0, 0, 0);
      sa[s] = x;
      float4v y = (float4v){0.f, 0.f, 0.f, 0.f};
      y = __builtin_amdgcn_mfma_f32_16x16x32_bf16(kr0[s], qf0b, y, 0, 0, 0);
      y = __builtin_amdgcn_mfma_f32_16x16x32_bf16(kr1[s], qf1b, y, 0, 0, 0);
      sb[s] = y;
    }
    __builtin_amdgcn_s_setprio(0);

    // --- prefetch V,K for next tile (wraps within split; harmless) ---
    const int nkv = kvbase + (((t + 1) & (S_LEN / 2 / 64 - 1)) * 64);
    vr0 = *(const short8*)(Vb + (size_t)(nkv + 2 * va) * DK + vdb);
    vr1 = *(const short8*)(Vb + (size_t)(nkv + 2 * va + 1) * DK + vdb);
#pragma unroll
    for (int s = 0; s < 4; ++s) {
      kr0[s] = *(const short8*)(Kb + (size_t)(nkv + s * 16 + r16) * DK + g * 8);
      kr1[s] = *(const short8*)(Kb + (size_t)(nkv + s * 16 + r16) * DK + 32 + g * 8);
    }

    // --- per-lane tile max ---
    float mxa[4], mxb[4];
#pragma unroll
    for (int s = 0; s < 4; ++s) {
      mxa[s] = fmaxf(fmaxf(sa[s][0], sa[s][1]), fmaxf(sa[s][2], sa[s][3]));
      mxb[s] = fmaxf(fmaxf(sb[s][0], sb[s][1]), fmaxf(sb[s][2], sb[s][3]));
    }
    const float mta_l = fmaxf(fmaxf(mxa[0], mxa[1]), fmaxf(mxa[2], mxa[3]));
    const float mtb_l = fmaxf(fmaxf(mxb[0], mxb[1]), fmaxf(mxb[2], mxb[3]));

    const int okk = (mta_l <= m_a + 8.f) && (mtb_l <= m_b + 8.f);
    if (__all(okk)) {
      // fast path: keep old max (P bounded by 2^8); no rescale
#pragma unroll
      for (int s = 0; s < 4; ++s) {
        const float a0 = exp2f(sa[s][0] - m_a), a1 = exp2f(sa[s][1] - m_a);
        const float a2 = exp2f(sa[s][2] - m_a), a3 = exp2f(sa[s][3] - m_a);
        Plu[w][0][r16][s * 8 + g * 2]     = cvt2(a0, a1);
        Plu[w][0][r16][s * 8 + g * 2 + 1] = cvt2(a2, a3);
        const float b0 = exp2f(sb[s][0] - m_b), b1 = exp2f(sb[s][1] - m_b);
        const float b2 = exp2f(sb[s][2] - m_b), b3 = exp2f(sb[s][3] - m_b);
        Plu[w][1][r16][s * 8 + g * 2]     = cvt2(b0, b1);
        Plu[w][1][r16][s * 8 + g * 2 + 1] = cvt2(b2, b3);
      }
    } else {
      // full path: cross-lane max, rescale O and l accumulators
      float mta = fmaxf(mta_l, __shfl_xor(mta_l, 16));
      float mtb = fmaxf(mtb_l, __shfl_xor(mtb_l, 16));
      mta = fmaxf(mta, __shfl_xor(mta, 32));
      mtb = fmaxf(mtb, __shfl_xor(mtb, 32));
      const float mna = fmaxf(m_a, mta);
      const float mnb = fmaxf(m_b, mtb);
      const float ala = exp2f(m_a - mna);
      const float alb = exp2f(m_b - mnb);
      const float aa0 = __shfl(ala, g * 4 + 0), ab0 = __shfl(alb, g * 4 + 0);
      const float aa1 = __shfl(ala, g * 4 + 1), ab1 = __shfl(alb, g * 4 + 1);
      const float aa2 = __shfl(ala, g * 4 + 2), ab2 = __shfl(alb, g * 4 + 2);
      const float aa3 = __shfl(ala, g * 4 + 3), ab3 = __shfl(alb, g * 4 + 3);
#pragma unroll
      for (int j = 0; j < 4; ++j) {
        oa[j][0] *= aa0; oa[j][1] *= aa1; oa[j][2] *= aa2; oa[j][3] *= aa3;
        ob[j][0] *= ab0; ob[j][1] *= ab1; ob[j][2] *= ab2; ob[j][3] *= ab3;
      }
      lacc_a[0] *= aa0; lacc_a[1] *= aa1; lacc_a[2] *= aa2; lacc_a[3] *= aa3;
      lacc_b[0] *= ab0; lacc_b[1] *= ab1; lacc_b[2] *= ab2; lacc_b[3] *= ab3;
#pragma unroll
      for (int s = 0; s < 4; ++s) {
        const float a0 = exp2f(sa[s][0] - mna), a1 = exp2f(sa[s][1] - mna);
        const float a2 = exp2f(sa[s][2] - mna), a3 = exp2f(sa[s][3] - mna);
        Plu[w][0][r16][s * 8 + g * 2]     = cvt2(a0, a1);
        Plu[w][0][r16][s * 8 + g * 2 + 1] = cvt2(a2, a3);
        const float b0 = exp2f(sb[s][0] - mnb), b1 = exp2f(sb[s][1] - mnb);
        const float b2 = exp2f(sb[s][2] - mnb), b3 = exp2f(sb[s][3] - mnb);
        Plu[w][1][r16][s * 8 + g * 2]     = cvt2(b0, b1);
        Plu[w][1][r16][s * 8 + g * 2 + 1] = cvt2(b2, b3);
      }
      m_a = mna; m_b = mnb;
    }

    __syncthreads();

    // --- PV + l-sum ---
    __builtin_amdgcn_s_setprio(1);
#pragma unroll
    for (int kc = 0; kc < 2; ++kc) {
      const short8 pfa = __builtin_bit_cast(short8, *(const uint4v*)&Plu[w][0][r16][kc * 16 + g * 4]);
      const short8 pfb = __builtin_bit_cast(short8, *(const uint4v*)&Plu[w][1][r16][kc * 16 + g * 4]);
      lacc_a = __builtin_amdgcn_mfma_f32_16x16x32_bf16(pfa, ones8, lacc_a, 0, 0, 0);
      lacc_b = __builtin_amdgcn_mfma_f32_16x16x32_bf16(pfb, ones8, lacc_b, 0, 0, 0);
#pragma unroll
      for (int j = 0; j < 4; ++j) {
        const int h = (2 * j + (r16 >> 3)) & 7;
        const short8 vf = __builtin_bit_cast(short8,
            *(const uint4v*)&Vtu[buf][j * 16 + r16][4 * (((kc << 2) + g) ^ h)]);
        oa[j] = __builtin_amdgcn_mfma_f32_16x16x32_bf16(pfa, vf, oa[j], 0, 0, 0);
        ob[j] = __builtin_amdgcn_mfma_f32_16x16x32_bf16(pfb, vf, ob[j], 0, 0, 0);
      }
    }
    __builtin_amdgcn_s_setprio(0);
  }

  // --- finalize split: normalized O + lse, nt stores (write-once data) ---
  const float ria0 = 1.f / lacc_a[0], rib0 = 1.f / lacc_b[0];
  const float ria1 = 1.f / lacc_a[1], rib1 = 1.f / lacc_b[1];
  const float ria2 = 1.f / lacc_a[2], rib2 = 1.f / lacc_b[2];
  const float ria3 = 1.f / lacc_a[3], rib3 = 1.f / lacc_b[3];
  const int b = bh >> 4, h = bh & 15;
#pragma unroll
  for (int j = 0; j < 4; ++j) {
    const int d = h * DK + j * 16 + r16;
    const int qa = q0 + g * 4;
    const int qb2 = q0 + 16 + g * 4;
    __builtin_nontemporal_store(f2b(oa[j][0] * ria0), &op[(size_t)(b * S_LEN + qa + 0) * EMB + d]);
    __builtin_nontemporal_store(f2b(oa[j][1] * ria1), &op[(size_t)(b * S_LEN + qa + 1) * EMB + d]);
    __builtin_nontemporal_store(f2b(oa[j][2] * ria2), &op[(size_t)(b * S_LEN + qa + 2) * EMB + d]);
    __builtin_nontemporal_store(f2b(oa[j][3] * ria3), &op[(size_t)(b * S_LEN + qa + 3) * EMB + d]);
    __builtin_nontemporal_store(f2b(ob[j][0] * rib0), &op[(size_t)(b * S_LEN + qb2 + 0) * EMB + d]);
    __builtin_nontemporal_store(f2b(ob[j][1] * rib1), &op[(size_t)(b * S_LEN + qb2 + 1) * EMB + d]);
    __builtin_nontemporal_store(f2b(ob[j][2] * rib2), &op[(size_t)(b * S_LEN + qb2 + 2) * EMB + d]);
    __builtin_nontemporal_store(f2b(ob[j][3] * rib3), &op[(size_t)(b * S_LEN + qb2 + 3) * EMB + d]);
  }

  // m broadcasts with ALL lanes active (r12 fix), predicated nt store.
  const float sma0 = __shfl(m_a, g * 4 + 0), smb0 = __shfl(m_b, g * 4 + 0);
  const float sma1 = __shfl(m_a, g * 4 + 1), smb1 = __shfl(m_b, g * 4 + 1);
  const float sma2 = __shfl(m_a, g * 4 + 2), smb2 = __shfl(m_b, g * 4 + 2);
  const float sma3 = __shfl(m_a, g * 4 + 3), smb3 = __shfl(m_b, g * 4 + 3);
  if (r16 == 0) {
    float* lp = lseB + (size_t)split * (BATCH * NH * S_LEN) + (size_t)bh * S_LEN;
    __builtin_nontemporal_store(sma0 + __log2f(lacc_a[0]), &lp[q0 + g * 4 + 0]);
    __builtin_nontemporal_store(sma1 + __log2f(lacc_a[1]), &lp[q0 + g * 4 + 1]);
    __builtin_nontemporal_store(sma2 + __log2f(lacc_a[2]), &lp[q0 + g * 4 + 2]);
    __builtin_nontemporal_store(sma3 + __log2f(lacc_a[3]), &lp[q0 + g * 4 + 3]);
    __builtin_nontemporal_store(smb0 + __log2f(lacc_b[0]), &lp[q0 + 16 + g * 4 + 0]);
    __builtin_nontemporal_store(smb1 + __log2f(lacc_b[1]), &lp[q0 + 16 + g * 4 + 1]);
    __builtin_nontemporal_store(smb2 + __log2f(lacc_b[2]), &lp[q0 + 16 + g * 4 + 2]);
    __builtin_nontemporal_store(smb3 + __log2f(lacc_b[3]), &lp[q0 + 16 + g * 4 + 3]);
  }
}

// ---------------------------------------------------------------------------
// Combine the two kv-splits: O = (O0*2^(lse0-m) + O1*2^(lse1-m)) / (sum w).
// nt loads (read-once streams); normal store of Cx (reused by gemm_out).
// ---------------------------------------------------------------------------
__global__ __launch_bounds__(256) void combine2(const short* __restrict__ op1,
                                                const float* __restrict__ lseB,
                                                short* __restrict__ cx /* = op0 */)
{
  const int c = blockIdx.x * 256 + threadIdx.x;   // 8-elem chunk, exact cover
  const size_t e = (size_t)c * 8;
  const int row = (int)(e >> 10);          // b*S + s
  const int col = (int)(e & 1023);
  const int h = col >> 6;
  const int b = row >> 11, s = row & (S_LEN - 1);
  const int li = (b * NH + h) * S_LEN + s;
  const float l0 = lseB[li];
  const float l1 = lseB[BATCH * NH * S_LEN + li];
  const float wm = fmaxf(l0, l1);
  const float w0 = exp2f(l0 - wm), w1 = exp2f(l1 - wm);
  const float inv = 1.f / (w0 + w1);
  const float f0 = w0 * inv, f1 = w1 * inv;
  const short8 a = __builtin_nontemporal_load((const short8*)(cx + e));
  const short8 d = __builtin_nontemporal_load((const short8*)(op1 + e));
  short8 o;
#pragma unroll
  for (int i = 0; i < 8; ++i)
    o[i] = f2b(b2f(a[i]) * f0 + b2f(d[i]) * f1);
  *(short8*)(cx + e) = o;
}

// ---------------------------------------------------------------------------
extern "C" void kernel_launch(void* const* d_in, const int* in_sizes, int n_in,
                              void* d_out, int out_size, void* d_ws, size_t ws_size,
                              hipStream_t stream)
{
  const float* q  = (const float*)d_in[0];
  const float* k  = (const float*)d_in[1];
  const float* v  = (const float*)d_in[2];
  const float* Wq = (const float*)d_in[3];
  const float* bq = (const float*)d_in[4];
  const float* Wk = (const float*)d_in[5];
  const float* bk = (const float*)d_in[6];
  const float* Wv = (const float*)d_in[7];
  const float* bv = (const float*)d_in[8];
  const float* Wo = (const float*)d_in[9];
  const float* bo = (const float*)d_in[10];

  short* ws = (short*)d_ws;
  const size_t WSZ  = (size_t)EMB * EMB;   // 1M elems per weight matrix
  const size_t PROJ = (size_t)MTOT * EMB;  // 4M elems per activation
  short* Wb   = ws;                // bf16 weights: Wq,Wk,Wv consecutive + Wo
  short* Wob  = ws + 3 * WSZ;
  short* Qp   = ws + 4 * WSZ;      // (B,H,S,DK) bf16, pre-scaled
  short* Vp   = Qp + PROJ;
  short* Cx   = Vp + PROJ;         // split-0 partial O, then combined context
  // lse buffer (512 KB) aliases the Wq-bf16 region: Wq copy is consumed by
  // gemm_qkv before attn writes lse; cvt_w4 rewrites it every call.
  float* lseB = (float*)ws;
  short* Kp   = (short*)d_out;                // K parks in d_out lower half
  short* Op1  = (short*)d_out + PROJ;         // split-1 partial O, upper half

  cvt_w4<<<dim3((int)(WSZ / 4 / 256), 4), dim3(256), 0, stream>>>(Wq, Wk, Wv, Wo, ws);

  gemm_qkv<<<dim3(768), dim3(256), 0, stream>>>(q, k, v, Wb, bq, bk, bv, Qp, Kp, Vp);
  attn_kernel<<<dim3(1024), dim3(256), 0, stream>>>(Qp, Kp, Vp, Cx, Op1, lseB);
  combine2<<<dim3((int)(PROJ / 8 / 256)), dim3(256), 0, stream>>>(Op1, lseB, Cx);
  gemm_out<<<dim3(256), dim3(256), 0, stream>>>(Cx, Wob, bo, (float*)d_out);
}

// Round 15
// 145.838 us; speedup vs baseline: 2.7901x; 1.2224x over previous
//
#include <hip/hip_runtime.h>
#include <stdint.h>

// Problem constants
#define S_LEN 2048
#define EMB   1024
#define NH    16
#define DK    64
#define BATCH 2
#define MTOT  (BATCH * S_LEN)  // 4096

typedef __attribute__((ext_vector_type(8))) short    short8;
typedef __attribute__((ext_vector_type(4))) float    f32x4;
typedef __attribute__((ext_vector_type(4))) float    float4v;
typedef __attribute__((ext_vector_type(4))) unsigned uint4v;
typedef __attribute__((ext_vector_type(2))) unsigned uint2v;

typedef __attribute__((address_space(1))) const unsigned gu32;
typedef __attribute__((address_space(3))) unsigned       lu32;

__device__ __forceinline__ short f2b(float f) {
  unsigned u = __builtin_bit_cast(unsigned, f);
  u = (u + 0x7FFFu + ((u >> 16) & 1u)) >> 16;  // RNE to bf16
  return (short)u;
}
// pack two f32 -> two bf16 in one uint (low = a, high = b)
__device__ __forceinline__ unsigned cvt2(float a, float b) {
  unsigned r;
  asm("v_cvt_pk_bf16_f32 %0, %1, %2" : "=v"(r) : "v"(a), "v"(b));
  return r;
}
// async global->LDS, 16B per lane; LDS dest = wave-uniform base + lane*16
__device__ __forceinline__ void gload16(const short* gp, short* lp) {
  __builtin_amdgcn_global_load_lds((gu32*)gp, (lu32*)lp, 16, 0, 0);
}

// ---------------------------------------------------------------------------
// Fused f32 -> bf16 weight convert: grid (WSZ/4/256, 4), y picks the matrix.
// ---------------------------------------------------------------------------
__global__ __launch_bounds__(256) void cvt_w4(const float* __restrict__ w0,
                                              const float* __restrict__ w1,
                                              const float* __restrict__ w2,
                                              const float* __restrict__ w3,
                                              short* __restrict__ dst)
{
  const size_t WSZ = (size_t)EMB * EMB;
  const int y = blockIdx.y;
  const float* src = (y == 0) ? w0 : (y == 1) ? w1 : (y == 2) ? w2 : w3;
  short* d = dst + (size_t)y * WSZ;
  const int i = blockIdx.x * 256 + threadIdx.x;  // exact cover, no tail
  const f32x4 v = *(const f32x4*)(src + (size_t)i * 4);
  uint2v p;
  p[0] = cvt2(v[0], v[1]);
  p[1] = cvt2(v[2], v[3]);
  *(uint2v*)(d + (size_t)i * 4) = p;
}

// ---------------------------------------------------------------------------
// NT-GEMM body with global_load_lds staging (m97 lever, rule-21 swizzle).
// W (and A in MODE 1) live in LDS as row-major [128][64] bf16 with XOR
// swizzle: data chunk c (8 bf16) of row r is at slot c^(r&7). The gload
// writes linearly (lane l -> base + l*16B); lane l therefore FETCHES global
// chunk (l&7)^(l>>3) of row (l>>3) in its wave's 8-row group, so the
// permutation is applied on the SOURCE address. Fragment reads apply the
// same XOR -> bank data-volume floor.
// MODE 0: A = f32, reg-staged + cvt into chunk-major LDS (unchanged r8 path);
//         W via gload. out = bf16 scattered (B,H,S,DK), scale applied.
// MODE 1: A = bf16 via gload; W via gload. out = f32 row-major (M,N).
// ---------------------------------------------------------------------------
template <int MODE>
__device__ __forceinline__ void gemm_body(const float* __restrict__ Af0,
                                          const short* __restrict__ Ab0,
                                          const short* __restrict__ W,
                                          const float* __restrict__ bias,
                                          short* __restrict__ outb,
                                          float* __restrict__ outf,
                                          float scale, int m0, int n0)
{
  __shared__ __align__(16) short Abuf[128 * 64];  // 16 KB (layout per MODE)
  __shared__ __align__(16) short Wl[128 * 64];    // 16 KB swizzled row-major
  const int tid = threadIdx.x;
  const int w = tid >> 6, l = tid & 63;
  const int g = l >> 4, r16 = l & 15;
  const int wr = w >> 1, wc = w & 1;
  const int srow = tid >> 3, shc = tid & 7;
  const int cs = shc ^ (srow & 7);          // inverse-swizzled source chunk

  float4v acc[4][4];
#pragma unroll
  for (int i = 0; i < 4; ++i)
#pragma unroll
    for (int j = 0; j < 4; ++j)
      acc[i][j] = (float4v){0.f, 0.f, 0.f, 0.f};

  const float* Af = Af0 + (size_t)m0 * EMB;
  const short* Ab = Ab0 + (size_t)m0 * EMB;
  const short* Wbase = W + (size_t)n0 * EMB;

  f32x4 ax[4][2];  // MODE 0 raw A staging regs
  if constexpr (MODE == 0) {
#pragma unroll
    for (int p = 0; p < 4; ++p) {
      const float* src = Af + (size_t)(p * 32 + srow) * EMB + shc * 8;
      ax[p][0] = *(const f32x4*)src;
      ax[p][1] = *(const f32x4*)(src + 4);
    }
  }

  for (int k0 = 0; k0 < EMB; k0 += 64) {
    uint4v awr[4];
    if constexpr (MODE == 0) {
#pragma unroll
      for (int p = 0; p < 4; ++p) {
        awr[p][0] = cvt2(ax[p][0][0], ax[p][0][1]);
        awr[p][1] = cvt2(ax[p][0][2], ax[p][0][3]);
        awr[p][2] = cvt2(ax[p][1][0], ax[p][1][1]);
        awr[p][3] = cvt2(ax[p][1][2], ax[p][1][3]);
      }
    }

    __syncthreads();   // previous tile's MFMAs done with LDS

    // async W staging for THIS tile (and A in MODE 1)
#pragma unroll
    for (int p = 0; p < 4; ++p) {
      gload16(Wbase + (size_t)(p * 32 + srow) * EMB + k0 + cs * 8,
              &Wl[(p * 32 + w * 8) * 64]);
      if constexpr (MODE == 1)
        gload16(Ab + (size_t)(p * 32 + srow) * EMB + k0 + cs * 8,
                &Abuf[(p * 32 + w * 8) * 64]);
    }
    if constexpr (MODE == 0) {
      // A chunk-major from regs: [chunk 8][row 128][8 shorts]
#pragma unroll
      for (int p = 0; p < 4; ++p)
        *(uint4v*)&Abuf[shc * 1024 + (p * 32 + srow) * 8] = awr[p];
    }

    __syncthreads();   // drains gload_lds (vmcnt) + ds writes

    if constexpr (MODE == 0) {
      if (k0 + 64 < EMB) {
        const int kn = k0 + 64;
#pragma unroll
        for (int p = 0; p < 4; ++p) {
          const float* src = Af + (size_t)(p * 32 + srow) * EMB + kn + shc * 8;
          ax[p][0] = *(const f32x4*)src;
          ax[p][1] = *(const f32x4*)(src + 4);
        }
      }
    }

    __builtin_amdgcn_s_setprio(1);
#pragma unroll
    for (int ks = 0; ks < 2; ++ks) {
      short8 af[4], bf[4];
#pragma unroll
      for (int i = 0; i < 4; ++i) {
        const int row = wr * 64 + i * 16 + r16;
        if constexpr (MODE == 0) {
          af[i] = __builtin_bit_cast(short8,
              *(const uint4v*)&Abuf[(ks * 4 + g) * 1024 + row * 8]);
        } else {
          const int sc = (ks * 4 + g) ^ (r16 & 7);
          af[i] = __builtin_bit_cast(short8,
              *(const uint4v*)&Abuf[row * 64 + sc * 8]);
        }
      }
#pragma unroll
      for (int j = 0; j < 4; ++j) {
        const int row = wc * 64 + j * 16 + r16;
        const int sc = (ks * 4 + g) ^ (r16 & 7);
        bf[j] = __builtin_bit_cast(short8,
            *(const uint4v*)&Wl[row * 64 + sc * 8]);
      }
#pragma unroll
      for (int i = 0; i < 4; ++i)
#pragma unroll
        for (int j = 0; j < 4; ++j)
          acc[i][j] = __builtin_amdgcn_mfma_f32_16x16x32_bf16(af[i], bf[j], acc[i][j], 0, 0, 0);
    }
    __builtin_amdgcn_s_setprio(0);
  }

  // Epilogue: C/D layout col = l&15, row = (l>>4)*4 + r
#pragma unroll
  for (int j = 0; j < 4; ++j) {
    const int n = n0 + wc * 64 + j * 16 + r16;
    const float bv = bias[n];
#pragma unroll
    for (int i = 0; i < 4; ++i) {
#pragma unroll
      for (int r = 0; r < 4; ++r) {
        const int m = m0 + wr * 64 + i * 16 + g * 4 + r;
        const float vv = (acc[i][j][r] + bv) * scale;
        if constexpr (MODE == 0) {
          const int b = m >> 11, s = m & (S_LEN - 1);
          const int h = n >> 6, d = n & (DK - 1);
          outb[(size_t)((b * NH + h) * S_LEN + s) * DK + d] = f2b(vv);
        } else {
          outf[(size_t)m * EMB + n] = vv;
        }
      }
    }
  }
}

// Fused Q/K/V projections: grid 768 blocks.
// Q output pre-scaled by (1/sqrt(dk)) * log2(e) for exp2-domain softmax.
__global__ __launch_bounds__(256, 2) void gemm_qkv(const float* __restrict__ q,
                                                   const float* __restrict__ k,
                                                   const float* __restrict__ v,
                                                   const short* __restrict__ Wb,
                                                   const float* __restrict__ bq,
                                                   const float* __restrict__ bk,
                                                   const float* __restrict__ bv,
                                                   short* __restrict__ Qp,
                                                   short* __restrict__ Kp,
                                                   short* __restrict__ Vp)
{
  const int which = blockIdx.x >> 8;
  const int inner = blockIdx.x & 255;
  const int lin = (inner & 7) * 32 + (inner >> 3);  // XCD swizzle
  const int m0 = (lin >> 3) * 128, n0 = (lin & 7) * 128;
  const float* A    = (which == 0) ? q  : (which == 1) ? k  : v;
  const float* bias = (which == 0) ? bq : (which == 1) ? bk : bv;
  short* out        = (which == 0) ? Qp : (which == 1) ? Kp : Vp;
  const short* W = Wb + (size_t)which * EMB * EMB;
  const float scale = (which == 0) ? 0.125f * 1.44269504088896f : 1.0f;
  gemm_body<0>(A, nullptr, W, bias, out, nullptr, scale, m0, n0);
}

__global__ __launch_bounds__(256, 2) void gemm_out(const short* __restrict__ Cx,
                                                   const short* __restrict__ Wob,
                                                   const float* __restrict__ bo,
                                                   float* __restrict__ outp)
{
  const int lin = (blockIdx.x & 7) * 32 + (blockIdx.x >> 3);
  gemm_body<1>(nullptr, Cx, Wob, bo, nullptr, outp, 1.0f, (lin >> 3) * 128, (lin & 7) * 128);
}

// ---------------------------------------------------------------------------
// Flash attention (reverted to the round-10 known-good: 89 us measured).
// Grid 512 XCD-swizzled, 32 q-rows/wave (two 16-row subtiles a/b sharing one
// K/V stream), defer-max (THR=8, exp2 domain), row-sums via MFMA ones-column,
// K frags + Vtu b128 reads shared across subtiles, double-buffered V^T,
// ONE barrier/iter, setprio on MFMA clusters. No kv-split (r11-r14 showed
// the split nets negative: occupancy gain doesn't materialize and combine
// adds overhead).
// ---------------------------------------------------------------------------
__global__ __launch_bounds__(256, 2) void attn_kernel(const short* __restrict__ Qp,
                                                      const short* __restrict__ Kp,
                                                      const short* __restrict__ Vp,
                                                      short* __restrict__ ctx)
{
  __shared__ __align__(16) unsigned Vtu[2][64][36];     // 18432 B
  __shared__ __align__(16) unsigned Plu[4][2][16][36];  // 18432 B
  const int tid = threadIdx.x;
  const int w = tid >> 6, l = tid & 63;
  const int g = l >> 4, r16 = l & 15;
  const int lin = (blockIdx.x & 7) * 64 + (blockIdx.x >> 3);  // XCD swizzle
  const int bh = lin >> 4;                          // b*NH + h (4 per XCD)
  const int q0 = (lin & 15) * 128 + w * 32;         // wave's 32 q rows
  const short* Qb = Qp + (size_t)bh * S_LEN * DK;
  const short* Kb = Kp + (size_t)bh * S_LEN * DK;
  const short* Vb = Vp + (size_t)bh * S_LEN * DK;

  const short8 qf0a = *(const short8*)(Qb + (size_t)(q0 + r16) * DK + g * 8);
  const short8 qf1a = *(const short8*)(Qb + (size_t)(q0 + r16) * DK + 32 + g * 8);
  const short8 qf0b = *(const short8*)(Qb + (size_t)(q0 + 16 + r16) * DK + g * 8);
  const short8 qf1b = *(const short8*)(Qb + (size_t)(q0 + 16 + r16) * DK + 32 + g * 8);

  const short one_b = (short)0x3F80;
  const short8 ones8 = {one_b, one_b, one_b, one_b, one_b, one_b, one_b, one_b};

  float4v oa[4], ob[4];
#pragma unroll
  for (int j = 0; j < 4; ++j) {
    oa[j] = (float4v){0.f, 0.f, 0.f, 0.f};
    ob[j] = (float4v){0.f, 0.f, 0.f, 0.f};
  }
  float4v lacc_a = (float4v){0.f, 0.f, 0.f, 0.f};
  float4v lacc_b = (float4v){0.f, 0.f, 0.f, 0.f};
  float m_a = -3.0e38f, m_b = -3.0e38f;   // running max for q = l&15

  const int va  = tid >> 3;
  const int vdb = (tid & 7) * 8;
  const int vcs = va ^ ((tid & 7) << 2);

  // --- prefetch tile 0 ---
  short8 vr0 = *(const short8*)(Vb + (size_t)(2 * va) * DK + vdb);
  short8 vr1 = *(const short8*)(Vb + (size_t)(2 * va + 1) * DK + vdb);
  short8 kr0[4], kr1[4];
#pragma unroll
  for (int s = 0; s < 4; ++s) {
    kr0[s] = *(const short8*)(Kb + (size_t)(s * 16 + r16) * DK + g * 8);
    kr1[s] = *(const short8*)(Kb + (size_t)(s * 16 + r16) * DK + 32 + g * 8);
  }

  for (int t = 0; t < S_LEN / 64; ++t) {
    const int buf = t & 1;
#pragma unroll
    for (int i = 0; i < 8; ++i) {
      const unsigned pk = ((unsigned)(unsigned short)vr0[i]) |
                          (((unsigned)(unsigned short)vr1[i]) << 16);
      Vtu[buf][vdb + i][vcs] = pk;
    }

    // --- QK^T both subtiles, shared K fragments ---
    float4v sa[4], sb[4];
    __builtin_amdgcn_s_setprio(1);
#pragma unroll
    for (int s = 0; s < 4; ++s) {
      float4v x = (float4v){0.f, 0.f, 0.f, 0.f};
      x = __builtin_amdgcn_mfma_f32_16x16x32_bf16(kr0[s], qf0a, x, 0, 0, 0);
      x = __builtin_amdgcn_mfma_f32_16x16x32_bf16(kr1[s], qf1a, x, 0, 0, 0);
      sa[s] = x;
      float4v y = (float4v){0.f, 0.f, 0.f, 0.f};
      y = __builtin_amdgcn_mfma_f32_16x16x32_bf16(kr0[s], qf0b, y, 0, 0, 0);
      y = __builtin_amdgcn_mfma_f32_16x16x32_bf16(kr1[s], qf1b, y, 0, 0, 0);
      sb[s] = y;
    }
    __builtin_amdgcn_s_setprio(0);

    // --- prefetch V,K for tile t+1 (wraps on last iter; harmless) ---
    const int nkv = ((t + 1) * 64) & (S_LEN - 1);
    vr0 = *(const short8*)(Vb + (size_t)(nkv + 2 * va) * DK + vdb);
    vr1 = *(const short8*)(Vb + (size_t)(nkv + 2 * va + 1) * DK + vdb);
#pragma unroll
    for (int s = 0; s < 4; ++s) {
      kr0[s] = *(const short8*)(Kb + (size_t)(nkv + s * 16 + r16) * DK + g * 8);
      kr1[s] = *(const short8*)(Kb + (size_t)(nkv + s * 16 + r16) * DK + 32 + g * 8);
    }

    // --- per-lane tile max ---
    float mxa[4], mxb[4];
#pragma unroll
    for (int s = 0; s < 4; ++s) {
      mxa[s] = fmaxf(fmaxf(sa[s][0], sa[s][1]), fmaxf(sa[s][2], sa[s][3]));
      mxb[s] = fmaxf(fmaxf(sb[s][0], sb[s][1]), fmaxf(sb[s][2], sb[s][3]));
    }
    const float mta_l = fmaxf(fmaxf(mxa[0], mxa[1]), fmaxf(mxa[2], mxa[3]));
    const float mtb_l = fmaxf(fmaxf(mxb[0], mxb[1]), fmaxf(mxb[2], mxb[3]));

    const int okk = (mta_l <= m_a + 8.f) && (mtb_l <= m_b + 8.f);
    if (__all(okk)) {
      // fast path: keep old max (P bounded by 2^8); no rescale
#pragma unroll
      for (int s = 0; s < 4; ++s) {
        const float a0 = exp2f(sa[s][0] - m_a), a1 = exp2f(sa[s][1] - m_a);
        const float a2 = exp2f(sa[s][2] - m_a), a3 = exp2f(sa[s][3] - m_a);
        Plu[w][0][r16][s * 8 + g * 2]     = cvt2(a0, a1);
        Plu[w][0][r16][s * 8 + g * 2 + 1] = cvt2(a2, a3);
        const float b0 = exp2f(sb[s][0] - m_b), b1 = exp2f(sb[s][1] - m_b);
        const float b2 = exp2f(sb[s][2] - m_b), b3 = exp2f(sb[s][3] - m_b);
        Plu[w][1][r16][s * 8 + g * 2]     = cvt2(b0, b1);
        Plu[w][1][r16][s * 8 + g * 2 + 1] = cvt2(b2, b3);
      }
    } else {
      // full path: cross-lane max, rescale O and l accumulators
      float mta = fmaxf(mta_l, __shfl_xor(mta_l, 16));
      float mtb = fmaxf(mtb_l, __shfl_xor(mtb_l, 16));
      mta = fmaxf(mta, __shfl_xor(mta, 32));
      mtb = fmaxf(mtb, __shfl_xor(mtb, 32));
      const float mna = fmaxf(m_a, mta);
      const float mnb = fmaxf(m_b, mtb);
      const float ala = exp2f(m_a - mna);
      const float alb = exp2f(m_b - mnb);
      const float aa0 = __shfl(ala, g * 4 + 0), ab0 = __shfl(alb, g * 4 + 0);
      const float aa1 = __shfl(ala, g * 4 + 1), ab1 = __shfl(alb, g * 4 + 1);
      const float aa2 = __shfl(ala, g * 4 + 2), ab2 = __shfl(alb, g * 4 + 2);
      const float aa3 = __shfl(ala, g * 4 + 3), ab3 = __shfl(alb, g * 4 + 3);
#pragma unroll
      for (int j = 0; j < 4; ++j) {
        oa[j][0] *= aa0; oa[j][1] *= aa1; oa[j][2] *= aa2; oa[j][3] *= aa3;
        ob[j][0] *= ab0; ob[j][1] *= ab1; ob[j][2] *= ab2; ob[j][3] *= ab3;
      }
      lacc_a[0] *= aa0; lacc_a[1] *= aa1; lacc_a[2] *= aa2; lacc_a[3] *= aa3;
      lacc_b[0] *= ab0; lacc_b[1] *= ab1; lacc_b[2] *= ab2; lacc_b[3] *= ab3;
#pragma unroll
      for (int s = 0; s < 4; ++s) {
        const float a0 = exp2f(sa[s][0] - mna), a1 = exp2f(sa[s][1] - mna);
        const float a2 = exp2f(sa[s][2] - mna), a3 = exp2f(sa[s][3] - mna);
        Plu[w][0][r16][s * 8 + g * 2]     = cvt2(a0, a1);
        Plu[w][0][r16][s * 8 + g * 2 + 1] = cvt2(a2, a3);
        const float b0 = exp2f(sb[s][0] - mnb), b1 = exp2f(sb[s][1] - mnb);
        const float b2 = exp2f(sb[s][2] - mnb), b3 = exp2f(sb[s][3] - mnb);
        Plu[w][1][r16][s * 8 + g * 2]     = cvt2(b0, b1);
        Plu[w][1][r16][s * 8 + g * 2 + 1] = cvt2(b2, b3);
      }
      m_a = mna; m_b = mnb;
    }

    __syncthreads();

    // --- PV + l-sum ---
    __builtin_amdgcn_s_setprio(1);
#pragma unroll
    for (int kc = 0; kc < 2; ++kc) {
      const short8 pfa = __builtin_bit_cast(short8, *(const uint4v*)&Plu[w][0][r16][kc * 16 + g * 4]);
      const short8 pfb = __builtin_bit_cast(short8, *(const uint4v*)&Plu[w][1][r16][kc * 16 + g * 4]);
      lacc_a = __builtin_amdgcn_mfma_f32_16x16x32_bf16(pfa, ones8, lacc_a, 0, 0, 0);
      lacc_b = __builtin_amdgcn_mfma_f32_16x16x32_bf16(pfb, ones8, lacc_b, 0, 0, 0);
#pragma unroll
      for (int j = 0; j < 4; ++j) {
        const int h = (2 * j + (r16 >> 3)) & 7;
        const short8 vf = __builtin_bit_cast(short8,
            *(const uint4v*)&Vtu[buf][j * 16 + r16][4 * (((kc << 2) + g) ^ h)]);
        oa[j] = __builtin_amdgcn_mfma_f32_16x16x32_bf16(pfa, vf, oa[j], 0, 0, 0);
        ob[j] = __builtin_amdgcn_mfma_f32_16x16x32_bf16(pfb, vf, ob[j], 0, 0, 0);
      }
    }
    __builtin_amdgcn_s_setprio(0);
  }

  // --- finalize: lacc rows align with oacc C-layout rows ---
  const float ria0 = 1.f / lacc_a[0], rib0 = 1.f / lacc_b[0];
  const float ria1 = 1.f / lacc_a[1], rib1 = 1.f / lacc_b[1];
  const float ria2 = 1.f / lacc_a[2], rib2 = 1.f / lacc_b[2];
  const float ria3 = 1.f / lacc_a[3], rib3 = 1.f / lacc_b[3];
  const int b = bh >> 4, h = bh & 15;
#pragma unroll
  for (int j = 0; j < 4; ++j) {
    const int d = h * DK + j * 16 + r16;
    const int qa = q0 + g * 4;
    const int qb2 = q0 + 16 + g * 4;
    ctx[(size_t)(b * S_LEN + qa + 0) * EMB + d] = f2b(oa[j][0] * ria0);
    ctx[(size_t)(b * S_LEN + qa + 1) * EMB + d] = f2b(oa[j][1] * ria1);
    ctx[(size_t)(b * S_LEN + qa + 2) * EMB + d] = f2b(oa[j][2] * ria2);
    ctx[(size_t)(b * S_LEN + qa + 3) * EMB + d] = f2b(oa[j][3] * ria3);
    ctx[(size_t)(b * S_LEN + qb2 + 0) * EMB + d] = f2b(ob[j][0] * rib0);
    ctx[(size_t)(b * S_LEN + qb2 + 1) * EMB + d] = f2b(ob[j][1] * rib1);
    ctx[(size_t)(b * S_LEN + qb2 + 2) * EMB + d] = f2b(ob[j][2] * rib2);
    ctx[(size_t)(b * S_LEN + qb2 + 3) * EMB + d] = f2b(ob[j][3] * rib3);
  }
}

// ---------------------------------------------------------------------------
extern "C" void kernel_launch(void* const* d_in, const int* in_sizes, int n_in,
                              void* d_out, int out_size, void* d_ws, size_t ws_size,
                              hipStream_t stream)
{
  const float* q  = (const float*)d_in[0];
  const float* k  = (const float*)d_in[1];
  const float* v  = (const float*)d_in[2];
  const float* Wq = (const float*)d_in[3];
  const float* bq = (const float*)d_in[4];
  const float* Wk = (const float*)d_in[5];
  const float* bk = (const float*)d_in[6];
  const float* Wv = (const float*)d_in[7];
  const float* bv = (const float*)d_in[8];
  const float* Wo = (const float*)d_in[9];
  const float* bo = (const float*)d_in[10];

  short* ws = (short*)d_ws;
  const size_t WSZ  = (size_t)EMB * EMB;   // 1M elems per weight matrix
  const size_t PROJ = (size_t)MTOT * EMB;  // 4M elems per activation
  short* Wb  = ws;                 // bf16 weights: Wq,Wk,Wv consecutive + Wo
  short* Wob = ws + 3 * WSZ;
  short* Qp  = ws + 4 * WSZ;       // (B,H,S,DK) bf16, pre-scaled
  short* Vp  = Qp + PROJ;
  short* Cx  = Vp + PROJ;          // (B*S, E) bf16 context
  short* Kp  = (short*)d_out;      // K parks in d_out; consumed before final GEMM

  cvt_w4<<<dim3((int)(WSZ / 4 / 256), 4), dim3(256), 0, stream>>>(Wq, Wk, Wv, Wo, ws);

  gemm_qkv<<<dim3(768), dim3(256), 0, stream>>>(q, k, v, Wb, bq, bk, bv, Qp, Kp, Vp);
  attn_kernel<<<dim3(512), dim3(256), 0, stream>>>(Qp, Kp, Vp, Cx);
  gemm_out<<<dim3(256), dim3(256), 0, stream>>>(Cx, Wob, bo, (float*)d_out);
}

// Round 16
// 140.229 us; speedup vs baseline: 2.9017x; 1.0400x over previous
//
#include <hip/hip_runtime.h>
#include <stdint.h>

// Problem constants
#define S_LEN 2048
#define EMB   1024
#define NH    16
#define DK    64
#define BATCH 2
#define MTOT  (BATCH * S_LEN)  // 4096

typedef __attribute__((ext_vector_type(8))) short    short8;
typedef __attribute__((ext_vector_type(4))) float    f32x4;
typedef __attribute__((ext_vector_type(4))) float    float4v;
typedef __attribute__((ext_vector_type(4))) unsigned uint4v;
typedef __attribute__((ext_vector_type(2))) unsigned uint2v;

typedef __attribute__((address_space(1))) const unsigned gu32;
typedef __attribute__((address_space(3))) unsigned       lu32;

__device__ __forceinline__ short f2b(float f) {
  unsigned u = __builtin_bit_cast(unsigned, f);
  u = (u + 0x7FFFu + ((u >> 16) & 1u)) >> 16;  // RNE to bf16
  return (short)u;
}
// pack two f32 -> two bf16 in one uint (low = a, high = b)
__device__ __forceinline__ unsigned cvt2(float a, float b) {
  unsigned r;
  asm("v_cvt_pk_bf16_f32 %0, %1, %2" : "=v"(r) : "v"(a), "v"(b));
  return r;
}
// raw hardware exp2 (libm exp2f adds range-fixup VALU around v_exp_f32;
// our args are <= 8 on the fast path and -huge -> 0 on the full path)
__device__ __forceinline__ float ex2(float x) {
  float r;
  asm("v_exp_f32 %0, %1" : "=v"(r) : "v"(x));
  return r;
}
// async global->LDS, 16B per lane; LDS dest = wave-uniform base + lane*16
__device__ __forceinline__ void gload16(const short* gp, short* lp) {
  __builtin_amdgcn_global_load_lds((gu32*)gp, (lu32*)lp, 16, 0, 0);
}

// ---------------------------------------------------------------------------
// Fused f32 -> bf16 weight convert: grid (WSZ/4/256, 4), y picks the matrix.
// ---------------------------------------------------------------------------
__global__ __launch_bounds__(256) void cvt_w4(const float* __restrict__ w0,
                                              const float* __restrict__ w1,
                                              const float* __restrict__ w2,
                                              const float* __restrict__ w3,
                                              short* __restrict__ dst)
{
  const size_t WSZ = (size_t)EMB * EMB;
  const int y = blockIdx.y;
  const float* src = (y == 0) ? w0 : (y == 1) ? w1 : (y == 2) ? w2 : w3;
  short* d = dst + (size_t)y * WSZ;
  const int i = blockIdx.x * 256 + threadIdx.x;  // exact cover, no tail
  const f32x4 v = *(const f32x4*)(src + (size_t)i * 4);
  uint2v p;
  p[0] = cvt2(v[0], v[1]);
  p[1] = cvt2(v[2], v[3]);
  *(uint2v*)(d + (size_t)i * 4) = p;
}

// ---------------------------------------------------------------------------
// NT-GEMM body with global_load_lds staging (unchanged from round 15).
// W (and A in MODE 1) in LDS row-major [128][64] bf16, XOR swizzle c^(r&7):
// linear LDS dest + inverse-swizzled per-lane global SOURCE + same XOR on
// fragment reads (rule 21).
// MODE 0: A = f32 reg-staged + cvt into chunk-major LDS; W via gload.
// MODE 1: A and W via gload. out = f32 row-major (M,N).
// ---------------------------------------------------------------------------
template <int MODE>
__device__ __forceinline__ void gemm_body(const float* __restrict__ Af0,
                                          const short* __restrict__ Ab0,
                                          const short* __restrict__ W,
                                          const float* __restrict__ bias,
                                          short* __restrict__ outb,
                                          float* __restrict__ outf,
                                          float scale, int m0, int n0)
{
  __shared__ __align__(16) short Abuf[128 * 64];  // 16 KB (layout per MODE)
  __shared__ __align__(16) short Wl[128 * 64];    // 16 KB swizzled row-major
  const int tid = threadIdx.x;
  const int w = tid >> 6, l = tid & 63;
  const int g = l >> 4, r16 = l & 15;
  const int wr = w >> 1, wc = w & 1;
  const int srow = tid >> 3, shc = tid & 7;
  const int cs = shc ^ (srow & 7);          // inverse-swizzled source chunk

  float4v acc[4][4];
#pragma unroll
  for (int i = 0; i < 4; ++i)
#pragma unroll
    for (int j = 0; j < 4; ++j)
      acc[i][j] = (float4v){0.f, 0.f, 0.f, 0.f};

  const float* Af = Af0 + (size_t)m0 * EMB;
  const short* Ab = Ab0 + (size_t)m0 * EMB;
  const short* Wbase = W + (size_t)n0 * EMB;

  f32x4 ax[4][2];  // MODE 0 raw A staging regs
  if constexpr (MODE == 0) {
#pragma unroll
    for (int p = 0; p < 4; ++p) {
      const float* src = Af + (size_t)(p * 32 + srow) * EMB + shc * 8;
      ax[p][0] = *(const f32x4*)src;
      ax[p][1] = *(const f32x4*)(src + 4);
    }
  }

  for (int k0 = 0; k0 < EMB; k0 += 64) {
    uint4v awr[4];
    if constexpr (MODE == 0) {
#pragma unroll
      for (int p = 0; p < 4; ++p) {
        awr[p][0] = cvt2(ax[p][0][0], ax[p][0][1]);
        awr[p][1] = cvt2(ax[p][0][2], ax[p][0][3]);
        awr[p][2] = cvt2(ax[p][1][0], ax[p][1][1]);
        awr[p][3] = cvt2(ax[p][1][2], ax[p][1][3]);
      }
    }

    __syncthreads();   // previous tile's MFMAs done with LDS

    // async W staging for THIS tile (and A in MODE 1)
#pragma unroll
    for (int p = 0; p < 4; ++p) {
      gload16(Wbase + (size_t)(p * 32 + srow) * EMB + k0 + cs * 8,
              &Wl[(p * 32 + w * 8) * 64]);
      if constexpr (MODE == 1)
        gload16(Ab + (size_t)(p * 32 + srow) * EMB + k0 + cs * 8,
                &Abuf[(p * 32 + w * 8) * 64]);
    }
    if constexpr (MODE == 0) {
      // A chunk-major from regs: [chunk 8][row 128][8 shorts]
#pragma unroll
      for (int p = 0; p < 4; ++p)
        *(uint4v*)&Abuf[shc * 1024 + (p * 32 + srow) * 8] = awr[p];
    }

    __syncthreads();   // drains gload_lds (vmcnt) + ds writes

    if constexpr (MODE == 0) {
      if (k0 + 64 < EMB) {
        const int kn = k0 + 64;
#pragma unroll
        for (int p = 0; p < 4; ++p) {
          const float* src = Af + (size_t)(p * 32 + srow) * EMB + kn + shc * 8;
          ax[p][0] = *(const f32x4*)src;
          ax[p][1] = *(const f32x4*)(src + 4);
        }
      }
    }

    __builtin_amdgcn_s_setprio(1);
#pragma unroll
    for (int ks = 0; ks < 2; ++ks) {
      short8 af[4], bf[4];
#pragma unroll
      for (int i = 0; i < 4; ++i) {
        const int row = wr * 64 + i * 16 + r16;
        if constexpr (MODE == 0) {
          af[i] = __builtin_bit_cast(short8,
              *(const uint4v*)&Abuf[(ks * 4 + g) * 1024 + row * 8]);
        } else {
          const int sc = (ks * 4 + g) ^ (r16 & 7);
          af[i] = __builtin_bit_cast(short8,
              *(const uint4v*)&Abuf[row * 64 + sc * 8]);
        }
      }
#pragma unroll
      for (int j = 0; j < 4; ++j) {
        const int row = wc * 64 + j * 16 + r16;
        const int sc = (ks * 4 + g) ^ (r16 & 7);
        bf[j] = __builtin_bit_cast(short8,
            *(const uint4v*)&Wl[row * 64 + sc * 8]);
      }
#pragma unroll
      for (int i = 0; i < 4; ++i)
#pragma unroll
        for (int j = 0; j < 4; ++j)
          acc[i][j] = __builtin_amdgcn_mfma_f32_16x16x32_bf16(af[i], bf[j], acc[i][j], 0, 0, 0);
    }
    __builtin_amdgcn_s_setprio(0);
  }

  // Epilogue: C/D layout col = l&15, row = (l>>4)*4 + r
#pragma unroll
  for (int j = 0; j < 4; ++j) {
    const int n = n0 + wc * 64 + j * 16 + r16;
    const float bv = bias[n];
#pragma unroll
    for (int i = 0; i < 4; ++i) {
#pragma unroll
      for (int r = 0; r < 4; ++r) {
        const int m = m0 + wr * 64 + i * 16 + g * 4 + r;
        const float vv = (acc[i][j][r] + bv) * scale;
        if constexpr (MODE == 0) {
          const int b = m >> 11, s = m & (S_LEN - 1);
          const int h = n >> 6, d = n & (DK - 1);
          outb[(size_t)((b * NH + h) * S_LEN + s) * DK + d] = f2b(vv);
        } else {
          outf[(size_t)m * EMB + n] = vv;
        }
      }
    }
  }
}

// Fused Q/K/V projections: grid 768 blocks.
// Q output pre-scaled by (1/sqrt(dk)) * log2(e) for exp2-domain softmax.
__global__ __launch_bounds__(256, 2) void gemm_qkv(const float* __restrict__ q,
                                                   const float* __restrict__ k,
                                                   const float* __restrict__ v,
                                                   const short* __restrict__ Wb,
                                                   const float* __restrict__ bq,
                                                   const float* __restrict__ bk,
                                                   const float* __restrict__ bv,
                                                   short* __restrict__ Qp,
                                                   short* __restrict__ Kp,
                                                   short* __restrict__ Vp)
{
  const int which = blockIdx.x >> 8;
  const int inner = blockIdx.x & 255;
  const int lin = (inner & 7) * 32 + (inner >> 3);  // XCD swizzle
  const int m0 = (lin >> 3) * 128, n0 = (lin & 7) * 128;
  const float* A    = (which == 0) ? q  : (which == 1) ? k  : v;
  const float* bias = (which == 0) ? bq : (which == 1) ? bk : bv;
  short* out        = (which == 0) ? Qp : (which == 1) ? Kp : Vp;
  const short* W = Wb + (size_t)which * EMB * EMB;
  const float scale = (which == 0) ? 0.125f * 1.44269504088896f : 1.0f;
  gemm_body<0>(A, nullptr, W, bias, out, nullptr, scale, m0, n0);
}

__global__ __launch_bounds__(256, 2) void gemm_out(const short* __restrict__ Cx,
                                                   const short* __restrict__ Wob,
                                                   const float* __restrict__ bo,
                                                   float* __restrict__ outp)
{
  const int lin = (blockIdx.x & 7) * 32 + (blockIdx.x >> 3);
  gemm_body<1>(nullptr, Cx, Wob, bo, nullptr, outp, 1.0f, (lin >> 3) * 128, (lin & 7) * 128);
}

// ---------------------------------------------------------------------------
// Flash attention (r10/r15 known-good structure) + VALU/LDS-pipe diet:
//  - raw v_exp_f32 for all exp2 (kills libm fixup instrs; safe under
//    defer-max: fast-path args <= 8, full path -huge -> 0)
//  - P written as b64 pairs (8 LDS write instrs/wave-iter, was 16)
//  - affine prefetch addressing: nkv = (t+1)*64 with uniform t<31 guard
//    (the &-wrap blocked strength reduction -> 8 full 64-bit addr chains)
//  - left-nested fmax trees (v_max3 fusion)
// Grid 512 XCD-swizzled, 32 q-rows/wave, defer-max, MFMA ones-column l-sum,
// shared K frags + shared Vtu b128 reads, double-buffered V^T, 1 barrier.
// ---------------------------------------------------------------------------
__global__ __launch_bounds__(256, 2) void attn_kernel(const short* __restrict__ Qp,
                                                      const short* __restrict__ Kp,
                                                      const short* __restrict__ Vp,
                                                      short* __restrict__ ctx)
{
  __shared__ __align__(16) unsigned Vtu[2][64][36];     // 18432 B
  __shared__ __align__(16) unsigned Plu[4][2][16][36];  // 18432 B
  const int tid = threadIdx.x;
  const int w = tid >> 6, l = tid & 63;
  const int g = l >> 4, r16 = l & 15;
  const int lin = (blockIdx.x & 7) * 64 + (blockIdx.x >> 3);  // XCD swizzle
  const int bh = lin >> 4;                          // b*NH + h (4 per XCD)
  const int q0 = (lin & 15) * 128 + w * 32;         // wave's 32 q rows
  const short* Qb = Qp + (size_t)bh * S_LEN * DK;
  const short* Kb = Kp + (size_t)bh * S_LEN * DK;
  const short* Vb = Vp + (size_t)bh * S_LEN * DK;

  const short8 qf0a = *(const short8*)(Qb + (size_t)(q0 + r16) * DK + g * 8);
  const short8 qf1a = *(const short8*)(Qb + (size_t)(q0 + r16) * DK + 32 + g * 8);
  const short8 qf0b = *(const short8*)(Qb + (size_t)(q0 + 16 + r16) * DK + g * 8);
  const short8 qf1b = *(const short8*)(Qb + (size_t)(q0 + 16 + r16) * DK + 32 + g * 8);

  const short one_b = (short)0x3F80;
  const short8 ones8 = {one_b, one_b, one_b, one_b, one_b, one_b, one_b, one_b};

  float4v oa[4], ob[4];
#pragma unroll
  for (int j = 0; j < 4; ++j) {
    oa[j] = (float4v){0.f, 0.f, 0.f, 0.f};
    ob[j] = (float4v){0.f, 0.f, 0.f, 0.f};
  }
  float4v lacc_a = (float4v){0.f, 0.f, 0.f, 0.f};
  float4v lacc_b = (float4v){0.f, 0.f, 0.f, 0.f};
  float m_a = -3.0e38f, m_b = -3.0e38f;   // running max for q = l&15

  const int va  = tid >> 3;
  const int vdb = (tid & 7) * 8;
  const int vcs = va ^ ((tid & 7) << 2);

  // --- prefetch tile 0 ---
  short8 vr0 = *(const short8*)(Vb + (size_t)(2 * va) * DK + vdb);
  short8 vr1 = *(const short8*)(Vb + (size_t)(2 * va + 1) * DK + vdb);
  short8 kr0[4], kr1[4];
#pragma unroll
  for (int s = 0; s < 4; ++s) {
    kr0[s] = *(const short8*)(Kb + (size_t)(s * 16 + r16) * DK + g * 8);
    kr1[s] = *(const short8*)(Kb + (size_t)(s * 16 + r16) * DK + 32 + g * 8);
  }

  for (int t = 0; t < S_LEN / 64; ++t) {
    const int buf = t & 1;
#pragma unroll
    for (int i = 0; i < 8; ++i) {
      const unsigned pk = ((unsigned)(unsigned short)vr0[i]) |
                          (((unsigned)(unsigned short)vr1[i]) << 16);
      Vtu[buf][vdb + i][vcs] = pk;
    }

    // --- QK^T both subtiles, shared K fragments ---
    float4v sa[4], sb[4];
    __builtin_amdgcn_s_setprio(1);
#pragma unroll
    for (int s = 0; s < 4; ++s) {
      float4v x = (float4v){0.f, 0.f, 0.f, 0.f};
      x = __builtin_amdgcn_mfma_f32_16x16x32_bf16(kr0[s], qf0a, x, 0, 0, 0);
      x = __builtin_amdgcn_mfma_f32_16x16x32_bf16(kr1[s], qf1a, x, 0, 0, 0);
      sa[s] = x;
      float4v y = (float4v){0.f, 0.f, 0.f, 0.f};
      y = __builtin_amdgcn_mfma_f32_16x16x32_bf16(kr0[s], qf0b, y, 0, 0, 0);
      y = __builtin_amdgcn_mfma_f32_16x16x32_bf16(kr1[s], qf1b, y, 0, 0, 0);
      sb[s] = y;
    }
    __builtin_amdgcn_s_setprio(0);

    // --- prefetch V,K for tile t+1; affine addresses, uniform guard ---
    if (t < S_LEN / 64 - 1) {
      const int nkv = (t + 1) * 64;
      vr0 = *(const short8*)(Vb + (size_t)(nkv + 2 * va) * DK + vdb);
      vr1 = *(const short8*)(Vb + (size_t)(nkv + 2 * va + 1) * DK + vdb);
#pragma unroll
      for (int s = 0; s < 4; ++s) {
        kr0[s] = *(const short8*)(Kb + (size_t)(nkv + s * 16 + r16) * DK + g * 8);
        kr1[s] = *(const short8*)(Kb + (size_t)(nkv + s * 16 + r16) * DK + 32 + g * 8);
      }
    }

    // --- per-lane tile max (left-nested for v_max3 fusion) ---
    float mxa[4], mxb[4];
#pragma unroll
    for (int s = 0; s < 4; ++s) {
      mxa[s] = fmaxf(fmaxf(fmaxf(sa[s][0], sa[s][1]), sa[s][2]), sa[s][3]);
      mxb[s] = fmaxf(fmaxf(fmaxf(sb[s][0], sb[s][1]), sb[s][2]), sb[s][3]);
    }
    const float mta_l = fmaxf(fmaxf(fmaxf(mxa[0], mxa[1]), mxa[2]), mxa[3]);
    const float mtb_l = fmaxf(fmaxf(fmaxf(mxb[0], mxb[1]), mxb[2]), mxb[3]);

    const int okk = (mta_l <= m_a + 8.f) && (mtb_l <= m_b + 8.f);
    if (__all(okk)) {
      // fast path: keep old max (P bounded by 2^8); no rescale
#pragma unroll
      for (int s = 0; s < 4; ++s) {
        uint2v pwa, pwb;
        pwa[0] = cvt2(ex2(sa[s][0] - m_a), ex2(sa[s][1] - m_a));
        pwa[1] = cvt2(ex2(sa[s][2] - m_a), ex2(sa[s][3] - m_a));
        pwb[0] = cvt2(ex2(sb[s][0] - m_b), ex2(sb[s][1] - m_b));
        pwb[1] = cvt2(ex2(sb[s][2] - m_b), ex2(sb[s][3] - m_b));
        *(uint2v*)&Plu[w][0][r16][s * 8 + g * 2] = pwa;
        *(uint2v*)&Plu[w][1][r16][s * 8 + g * 2] = pwb;
      }
    } else {
      // full path: cross-lane max, rescale O and l accumulators
      float mta = fmaxf(mta_l, __shfl_xor(mta_l, 16));
      float mtb = fmaxf(mtb_l, __shfl_xor(mtb_l, 16));
      mta = fmaxf(mta, __shfl_xor(mta, 32));
      mtb = fmaxf(mtb, __shfl_xor(mtb, 32));
      const float mna = fmaxf(m_a, mta);
      const float mnb = fmaxf(m_b, mtb);
      const float ala = ex2(m_a - mna);
      const float alb = ex2(m_b - mnb);
      const float aa0 = __shfl(ala, g * 4 + 0), ab0 = __shfl(alb, g * 4 + 0);
      const float aa1 = __shfl(ala, g * 4 + 1), ab1 = __shfl(alb, g * 4 + 1);
      const float aa2 = __shfl(ala, g * 4 + 2), ab2 = __shfl(alb, g * 4 + 2);
      const float aa3 = __shfl(ala, g * 4 + 3), ab3 = __shfl(alb, g * 4 + 3);
#pragma unroll
      for (int j = 0; j < 4; ++j) {
        oa[j][0] *= aa0; oa[j][1] *= aa1; oa[j][2] *= aa2; oa[j][3] *= aa3;
        ob[j][0] *= ab0; ob[j][1] *= ab1; ob[j][2] *= ab2; ob[j][3] *= ab3;
      }
      lacc_a[0] *= aa0; lacc_a[1] *= aa1; lacc_a[2] *= aa2; lacc_a[3] *= aa3;
      lacc_b[0] *= ab0; lacc_b[1] *= ab1; lacc_b[2] *= ab2; lacc_b[3] *= ab3;
#pragma unroll
      for (int s = 0; s < 4; ++s) {
        uint2v pwa, pwb;
        pwa[0] = cvt2(ex2(sa[s][0] - mna), ex2(sa[s][1] - mna));
        pwa[1] = cvt2(ex2(sa[s][2] - mna), ex2(sa[s][3] - mna));
        pwb[0] = cvt2(ex2(sb[s][0] - mnb), ex2(sb[s][1] - mnb));
        pwb[1] = cvt2(ex2(sb[s][2] - mnb), ex2(sb[s][3] - mnb));
        *(uint2v*)&Plu[w][0][r16][s * 8 + g * 2] = pwa;
        *(uint2v*)&Plu[w][1][r16][s * 8 + g * 2] = pwb;
      }
      m_a = mna; m_b = mnb;
    }

    __syncthreads();

    // --- PV + l-sum ---
    __builtin_amdgcn_s_setprio(1);
#pragma unroll
    for (int kc = 0; kc < 2; ++kc) {
      const short8 pfa = __builtin_bit_cast(short8, *(const uint4v*)&Plu[w][0][r16][kc * 16 + g * 4]);
      const short8 pfb = __builtin_bit_cast(short8, *(const uint4v*)&Plu[w][1][r16][kc * 16 + g * 4]);
      lacc_a = __builtin_amdgcn_mfma_f32_16x16x32_bf16(pfa, ones8, lacc_a, 0, 0, 0);
      lacc_b = __builtin_amdgcn_mfma_f32_16x16x32_bf16(pfb, ones8, lacc_b, 0, 0, 0);
#pragma unroll
      for (int j = 0; j < 4; ++j) {
        const int h = (2 * j + (r16 >> 3)) & 7;
        const short8 vf = __builtin_bit_cast(short8,
            *(const uint4v*)&Vtu[buf][j * 16 + r16][4 * (((kc << 2) + g) ^ h)]);
        oa[j] = __builtin_amdgcn_mfma_f32_16x16x32_bf16(pfa, vf, oa[j], 0, 0, 0);
        ob[j] = __builtin_amdgcn_mfma_f32_16x16x32_bf16(pfb, vf, ob[j], 0, 0, 0);
      }
    }
    __builtin_amdgcn_s_setprio(0);
  }

  // --- finalize: lacc rows align with oacc C-layout rows ---
  const float ria0 = 1.f / lacc_a[0], rib0 = 1.f / lacc_b[0];
  const float ria1 = 1.f / lacc_a[1], rib1 = 1.f / lacc_b[1];
  const float ria2 = 1.f / lacc_a[2], rib2 = 1.f / lacc_b[2];
  const float ria3 = 1.f / lacc_a[3], rib3 = 1.f / lacc_b[3];
  const int b = bh >> 4, h = bh & 15;
#pragma unroll
  for (int j = 0; j < 4; ++j) {
    const int d = h * DK + j * 16 + r16;
    const int qa = q0 + g * 4;
    const int qb2 = q0 + 16 + g * 4;
    ctx[(size_t)(b * S_LEN + qa + 0) * EMB + d] = f2b(oa[j][0] * ria0);
    ctx[(size_t)(b * S_LEN + qa + 1) * EMB + d] = f2b(oa[j][1] * ria1);
    ctx[(size_t)(b * S_LEN + qa + 2) * EMB + d] = f2b(oa[j][2] * ria2);
    ctx[(size_t)(b * S_LEN + qa + 3) * EMB + d] = f2b(oa[j][3] * ria3);
    ctx[(size_t)(b * S_LEN + qb2 + 0) * EMB + d] = f2b(ob[j][0] * rib0);
    ctx[(size_t)(b * S_LEN + qb2 + 1) * EMB + d] = f2b(ob[j][1] * rib1);
    ctx[(size_t)(b * S_LEN + qb2 + 2) * EMB + d] = f2b(ob[j][2] * rib2);
    ctx[(size_t)(b * S_LEN + qb2 + 3) * EMB + d] = f2b(ob[j][3] * rib3);
  }
}

// ---------------------------------------------------------------------------
extern "C" void kernel_launch(void* const* d_in, const int* in_sizes, int n_in,
                              void* d_out, int out_size, void* d_ws, size_t ws_size,
                              hipStream_t stream)
{
  const float* q  = (const float*)d_in[0];
  const float* k  = (const float*)d_in[1];
  const float* v  = (const float*)d_in[2];
  const float* Wq = (const float*)d_in[3];
  const float* bq = (const float*)d_in[4];
  const float* Wk = (const float*)d_in[5];
  const float* bk = (const float*)d_in[6];
  const float* Wv = (const float*)d_in[7];
  const float* bv = (const float*)d_in[8];
  const float* Wo = (const float*)d_in[9];
  const float* bo = (const float*)d_in[10];

  short* ws = (short*)d_ws;
  const size_t WSZ  = (size_t)EMB * EMB;   // 1M elems per weight matrix
  const size_t PROJ = (size_t)MTOT * EMB;  // 4M elems per activation
  short* Wb  = ws;                 // bf16 weights: Wq,Wk,Wv consecutive + Wo
  short* Wob = ws + 3 * WSZ;
  short* Qp  = ws + 4 * WSZ;       // (B,H,S,DK) bf16, pre-scaled
  short* Vp  = Qp + PROJ;
  short* Cx  = Vp + PROJ;          // (B*S, E) bf16 context
  short* Kp  = (short*)d_out;      // K parks in d_out; consumed before final GEMM

  cvt_w4<<<dim3((int)(WSZ / 4 / 256), 4), dim3(256), 0, stream>>>(Wq, Wk, Wv, Wo, ws);

  gemm_qkv<<<dim3(768), dim3(256), 0, stream>>>(q, k, v, Wb, bq, bk, bv, Qp, Kp, Vp);
  attn_kernel<<<dim3(512), dim3(256), 0, stream>>>(Qp, Kp, Vp, Cx);
  gemm_out<<<dim3(256), dim3(256), 0, stream>>>(Cx, Wob, bo, (float*)d_out);
}